// Round 12
// baseline (1025.186 us; speedup 1.0000x reference)
//
#include <hip/hip_runtime.h>
#include <hip/hip_bf16.h>
#include <cstdint>

#define N_NODES 50000
#define E_EDGES 800000
#define R_REL   3
#define IN_F    128
#define HID_F   128
#define D_F     384
#define H_HEADS 8
#define O_PER   16
#define OUT_F   64
#define L_LAYERS 4
#define NBUCK   391    // ceil(50000/128)
#define M_PAD   50048  // 391*128
#define NRT     391    // row tiles
#define BIN_CHUNK 8192
#define NC_EXT  512    // 3*128 feature cols + 1 block of (48 elr + 80 pad)

typedef __attribute__((ext_vector_type(8))) short short8;
typedef __attribute__((ext_vector_type(8))) unsigned short ushort8;
typedef __attribute__((ext_vector_type(4))) float f32x4;
typedef _Float16 f16;
typedef __attribute__((ext_vector_type(2))) _Float16 h2v;
typedef __attribute__((ext_vector_type(8))) _Float16 h8;

// ---- float atomicMax encoding (monotonic uint mapping) ----
__device__ __forceinline__ unsigned encf(float f) {
    unsigned u = __float_as_uint(f);
    return (u & 0x80000000u) ? ~u : (u | 0x80000000u);
}
__device__ __forceinline__ float decf(unsigned u) {
    return __uint_as_float((u & 0x80000000u) ? (u ^ 0x80000000u) : ~u);
}

__device__ __forceinline__ void split2(float v, unsigned short& hi, unsigned short& lo) {
    const unsigned u = __float_as_uint(v);
    hi = (unsigned short)(u >> 16);
    const float r = v - __uint_as_float(u & 0xFFFF0000u);
    lo = (unsigned short)(__float_as_uint(r) >> 16);
}

// =====================================================================
// Split-bf16 MFMA GEMM: C = A @ B, block 128x128, BK=64, 4 waves.
// XCD-aware 1D grid: d -> xcd=d&7, j=d>>3, cb=j%NCB, rt=xcd+8*(j/NCB).
// PRESPLIT: A supplied as pre-split bf16 hi/lo (Ahi/Alo, stride K).
// OMODE 0: fp32 C.  OMODE 3: layer-fused tch + el/er + max.
// =====================================================================
template<int OMODE, bool NORM, bool PRESPLIT>
__global__ __launch_bounds__(256) void mfma_gemm(
    const float* __restrict__ A,
    const unsigned short* __restrict__ Ahi, const unsigned short* __restrict__ Alo,
    const unsigned short* __restrict__ Bhi, const unsigned short* __restrict__ Blo,
    float* __restrict__ C, f16* __restrict__ Ch, int M, int K, int NcC, int NCB,
    const float* __restrict__ nscale, const float* __restrict__ nbias,
    float* __restrict__ elb, float* __restrict__ erb,
    unsigned* __restrict__ mencb)
{
    const int d = blockIdx.x;
    const int xcd = d & 7;
    const int j = d >> 3;
    const int cb = j % NCB;
    const int rt = xcd + 8 * (j / NCB);
    if (rt >= NRT) return;
    const int col0 = cb * 128;
    const int row0 = rt * 128;

    __shared__ __align__(16) unsigned short sAh[128 * 64];
    __shared__ __align__(16) unsigned short sAl[128 * 64];
    __shared__ __align__(16) unsigned short sBh[128 * 64];
    __shared__ __align__(16) unsigned short sBl[128 * 64];

    const int t = threadIdx.x;
    const int lane = t & 63;
    const int w = t >> 6;
    const int wm = (w >> 1) * 64;
    const int wn = (w & 1) * 64;
    const unsigned short* bh = Bhi + (size_t)col0 * K;
    const unsigned short* bl = Blo + (size_t)col0 * K;

    f32x4 acc[4][4] = {};

    for (int k0 = 0; k0 < K; k0 += 64) {
        #pragma unroll
        for (int c = 0; c < 4; ++c) {
            const int lb = c * 256 + t;
            const int arow = lb >> 3;
            const int bkg = (lb & 7) ^ (arow & 7);
            const int grow = row0 + arow;
            if (PRESPLIT) {
                ushort8 vh, vl;
                #pragma unroll
                for (int q = 0; q < 8; ++q) { vh[q] = 0; vl[q] = 0; }
                if (grow < M) {
                    const size_t ao = (size_t)grow * K + k0 + bkg * 8;
                    vh = *(const ushort8*)(Ahi + ao);
                    vl = *(const ushort8*)(Alo + ao);
                }
                *(ushort8*)&sAh[lb * 8] = vh;
                *(ushort8*)&sAl[lb * 8] = vl;
            } else {
                float4 v0 = make_float4(0.f, 0.f, 0.f, 0.f), v1 = v0;
                if (grow < M) {
                    const float* ap = A + (size_t)grow * K + k0 + bkg * 8;
                    v0 = *(const float4*)ap;
                    v1 = *(const float4*)(ap + 4);
                }
                if (NORM) {
                    const float4 s0 = *(const float4*)(nscale + k0 + bkg * 8);
                    const float4 s1 = *(const float4*)(nscale + k0 + bkg * 8 + 4);
                    const float4 b0 = *(const float4*)(nbias + k0 + bkg * 8);
                    const float4 b1 = *(const float4*)(nbias + k0 + bkg * 8 + 4);
                    v0.x = fmaxf(fmaf(v0.x, s0.x, b0.x), 0.f);
                    v0.y = fmaxf(fmaf(v0.y, s0.y, b0.y), 0.f);
                    v0.z = fmaxf(fmaf(v0.z, s0.z, b0.z), 0.f);
                    v0.w = fmaxf(fmaf(v0.w, s0.w, b0.w), 0.f);
                    v1.x = fmaxf(fmaf(v1.x, s1.x, b1.x), 0.f);
                    v1.y = fmaxf(fmaf(v1.y, s1.y, b1.y), 0.f);
                    v1.z = fmaxf(fmaf(v1.z, s1.z, b1.z), 0.f);
                    v1.w = fmaxf(fmaf(v1.w, s1.w, b1.w), 0.f);
                }
                ushort8 vh, vl;
                unsigned short h_, l_;
                split2(v0.x, h_, l_); vh[0] = h_; vl[0] = l_;
                split2(v0.y, h_, l_); vh[1] = h_; vl[1] = l_;
                split2(v0.z, h_, l_); vh[2] = h_; vl[2] = l_;
                split2(v0.w, h_, l_); vh[3] = h_; vl[3] = l_;
                split2(v1.x, h_, l_); vh[4] = h_; vl[4] = l_;
                split2(v1.y, h_, l_); vh[5] = h_; vl[5] = l_;
                split2(v1.z, h_, l_); vh[6] = h_; vl[6] = l_;
                split2(v1.w, h_, l_); vh[7] = h_; vl[7] = l_;
                *(ushort8*)&sAh[lb * 8] = vh;
                *(ushort8*)&sAl[lb * 8] = vl;
            }
        }
        #pragma unroll
        for (int c = 0; c < 4; ++c) {
            const int lb = c * 256 + t;
            const int nrow = lb >> 3;
            const int bkg = (lb & 7) ^ (nrow & 7);
            const size_t go = (size_t)nrow * K + k0 + bkg * 8;
            *(ushort8*)&sBh[lb * 8] = *(const ushort8*)(bh + go);
            *(ushort8*)&sBl[lb * 8] = *(const ushort8*)(bl + go);
        }
        __syncthreads();
        const int g = lane >> 4;
        const int l15 = lane & 15;
        #pragma unroll
        for (int s = 0; s < 2; ++s) {
            short8 ah[4], al_[4], bhf[4], blf[4];
            #pragma unroll
            for (int mf = 0; mf < 4; ++mf) {
                const int rm = wm + mf * 16 + l15;
                const int idx = rm * 64 + ((s * 4 + g) ^ (rm & 7)) * 8;
                ah[mf]  = *(const short8*)&sAh[idx];
                al_[mf] = *(const short8*)&sAl[idx];
            }
            #pragma unroll
            for (int nf = 0; nf < 4; ++nf) {
                const int rn = wn + nf * 16 + l15;
                const int idx = rn * 64 + ((s * 4 + g) ^ (rn & 7)) * 8;
                bhf[nf] = *(const short8*)&sBh[idx];
                blf[nf] = *(const short8*)&sBl[idx];
            }
            #pragma unroll
            for (int mf = 0; mf < 4; ++mf)
                #pragma unroll
                for (int nf = 0; nf < 4; ++nf) {
                    acc[mf][nf] = __builtin_amdgcn_mfma_f32_16x16x32_bf16(
                        ah[mf], bhf[nf], acc[mf][nf], 0, 0, 0);
                    acc[mf][nf] = __builtin_amdgcn_mfma_f32_16x16x32_bf16(
                        ah[mf], blf[nf], acc[mf][nf], 0, 0, 0);
                    acc[mf][nf] = __builtin_amdgcn_mfma_f32_16x16x32_bf16(
                        al_[mf], bhf[nf], acc[mf][nf], 0, 0, 0);
                }
        }
        __syncthreads();
    }
    const int g4 = lane >> 4;
    const int l15 = lane & 15;
    if (OMODE == 0) {
        #pragma unroll
        for (int mf = 0; mf < 4; ++mf)
            #pragma unroll
            for (int j2 = 0; j2 < 4; ++j2) {
                const int row = row0 + wm + mf * 16 + g4 * 4 + j2;
                if (row < M) {
                    #pragma unroll
                    for (int nf = 0; nf < 4; ++nf)
                        C[(size_t)row * NcC + col0 + wn + nf * 16 + l15] = acc[mf][nf][j2];
                }
            }
    } else if (cb < 3) {
        #pragma unroll
        for (int mf = 0; mf < 4; ++mf)
            #pragma unroll
            for (int j2 = 0; j2 < 4; ++j2) {
                const int row = row0 + wm + mf * 16 + g4 * 4 + j2;
                if (row < M) {
                    #pragma unroll
                    for (int nf = 0; nf < 4; ++nf)
                        Ch[(size_t)row * 384 + col0 + wn + nf * 16 + l15] = (f16)acc[mf][nf][j2];
                }
            }
    } else {
        // elr block: cols c = wn + nf*16 + l15, valid c < 48.
        float mx[3] = {-3.0e38f, -3.0e38f, -3.0e38f};
        if (wn == 0) {
            #pragma unroll
            for (int nf = 0; nf < 3; ++nf) {
                const int c = nf * 16 + l15;
                const int which = (c >> 3) & 1;
                const int hh = c & 7;
                float* dst = (which == 0 ? elb : erb) + (size_t)nf * N_NODES * 8 + hh;
                #pragma unroll
                for (int mf = 0; mf < 4; ++mf)
                    #pragma unroll
                    for (int j2 = 0; j2 < 4; ++j2) {
                        const int row = row0 + wm + mf * 16 + g4 * 4 + j2;
                        if (row < M) {
                            const float v = acc[mf][nf][j2];
                            dst[(size_t)row * 8] = v;
                            mx[nf] = fmaxf(mx[nf], v);
                        }
                    }
            }
        }
        #pragma unroll
        for (int nf = 0; nf < 3; ++nf) {
            mx[nf] = fmaxf(mx[nf], __shfl_xor(mx[nf], 16, 64));
            mx[nf] = fmaxf(mx[nf], __shfl_xor(mx[nf], 32, 64));
        }
        __shared__ float smax[2][48];
        if (wn == 0 && g4 == 0) {
            const int wi = w >> 1;
            #pragma unroll
            for (int nf = 0; nf < 3; ++nf) smax[wi][nf * 16 + l15] = mx[nf];
        }
        __syncthreads();
        if (t < 6) {
            float m_ = -3.0e38f;
            #pragma unroll
            for (int i = 0; i < 8; ++i)
                m_ = fmaxf(m_, fmaxf(smax[0][t * 8 + i], smax[1][t * 8 + i]));
            atomicMax(&mencb[t], encf(m_));
        }
    }
}

// =====================================================================
// Weight preps
// =====================================================================
__global__ __launch_bounds__(256) void wsplit_kernel(
    const float* __restrict__ W, unsigned short* __restrict__ hi,
    unsigned short* __restrict__ lo, int K0, int N0, int total)
{
    const int t = blockIdx.x * 256 + threadIdx.x;
    if (t >= total) return;
    const int per = K0 * N0;
    const int m = t / per;
    const int rem = t - m * per;
    const int n = rem / K0;
    const int k = rem - n * K0;
    const float v = W[(size_t)m * per + (size_t)k * N0 + n];
    unsigned short h_, l_;
    split2(v, h_, l_);
    hi[t] = h_; lo[t] = l_;
}

__global__ __launch_bounds__(256) void wg_split_kernel(
    const float* __restrict__ Wg, unsigned short* __restrict__ hi,
    unsigned short* __restrict__ lo)
{
    const int t = blockIdx.x * 256 + threadIdx.x;
    const int total = L_LAYERS * 384 * 384;
    if (t >= total) return;
    const int l = t / (384 * 384);
    const int rem = t - l * 384 * 384;
    const int c = rem / 384;
    const int d = rem - c * 384;
    const int r = c >> 7, n = c & 127;
    const float v = Wg[(((size_t)(l * 3 + r) * 384 + d) * 128) + n];
    unsigned short h_, l_;
    split2(v, h_, l_);
    const size_t idx = ((size_t)l * NC_EXT + c) * 384 + d;
    hi[idx] = h_; lo[idx] = l_;
}

__global__ __launch_bounds__(256) void welr_build_kernel(
    const float* __restrict__ Wg, const float* __restrict__ al,
    const float* __restrict__ ar, unsigned short* __restrict__ hi,
    unsigned short* __restrict__ lo)
{
    const int t = blockIdx.x * 256 + threadIdx.x;
    const int total = L_LAYERS * 128 * 384;
    if (t >= total) return;
    const int l = t / (128 * 384);
    const int rem = t - l * (128 * 384);
    const int c = rem / 384;
    const int d = rem - c * 384;
    float v = 0.f;
    if (c < 48) {
        const int rel = c >> 4, which = (c >> 3) & 1, hh = c & 7;
        const float* wp = Wg + (((size_t)(l * 3 + rel) * 384 + d) * 128 + hh * 16);
        const float* ap = (which ? ar : al) + ((size_t)(l * 3 + rel) * 8 + hh) * 16;
        #pragma unroll
        for (int o = 0; o < 16; ++o) v += wp[o] * ap[o];
    }
    unsigned short h_, l_;
    split2(v, h_, l_);
    const size_t idx = ((size_t)l * NC_EXT + 384 + c) * 384 + d;
    hi[idx] = h_; lo[idx] = l_;
}

// =====================================================================
// fp32 VALU GEMM (dec2 only)
// =====================================================================
template<bool NORM>
__global__ __launch_bounds__(256) void gemm_kernel(
    const float* __restrict__ A, const float* __restrict__ B, float* __restrict__ C,
    int M, int Nc, int K,
    const float* __restrict__ nscale, const float* __restrict__ nbias)
{
    constexpr int BM = 128, BN = 64, BK = 16, TM = 8, TN = 4;
    __shared__ float As[BK][BM + 4];
    __shared__ float Bs[BK][BN];
    const int t = threadIdx.x;
    const int row0 = blockIdx.x * BM;
    const int col0 = blockIdx.y * BN;
    const int trow = t >> 4;
    const int tcol = t & 15;
    float acc[TM][TN] = {};
    const int arow = t >> 2;
    const int akq = t & 3;
    for (int k0 = 0; k0 < K; k0 += BK) {
        #pragma unroll
        for (int half = 0; half < 2; ++half) {
            const int row = arow + half * 64;
            const int grow = row0 + row;
            float4 v = make_float4(0.f, 0.f, 0.f, 0.f);
            if (grow < M)
                v = *(const float4*)(A + (size_t)grow * K + k0 + akq * 4);
            if (NORM) {
                const float4 sc = *(const float4*)(nscale + k0 + akq * 4);
                const float4 bi = *(const float4*)(nbias + k0 + akq * 4);
                v.x = fmaxf(fmaf(v.x, sc.x, bi.x), 0.f);
                v.y = fmaxf(fmaf(v.y, sc.y, bi.y), 0.f);
                v.z = fmaxf(fmaf(v.z, sc.z, bi.z), 0.f);
                v.w = fmaxf(fmaf(v.w, sc.w, bi.w), 0.f);
            }
            As[akq * 4 + 0][row] = v.x;
            As[akq * 4 + 1][row] = v.y;
            As[akq * 4 + 2][row] = v.z;
            As[akq * 4 + 3][row] = v.w;
        }
        {
            const int krow = t >> 4, c4 = t & 15;
            const float4 v = *(const float4*)(B + (size_t)(k0 + krow) * Nc + col0 + c4 * 4);
            *(float4*)&Bs[krow][c4 * 4] = v;
        }
        __syncthreads();
        #pragma unroll
        for (int k = 0; k < BK; ++k) {
            const float4 a0 = *(const float4*)&As[k][trow * TM];
            const float4 a1 = *(const float4*)&As[k][trow * TM + 4];
            const float4 b4 = *(const float4*)&Bs[k][tcol * TN];
            const float a[8] = {a0.x, a0.y, a0.z, a0.w, a1.x, a1.y, a1.z, a1.w};
            const float b[4] = {b4.x, b4.y, b4.z, b4.w};
            #pragma unroll
            for (int i = 0; i < TM; ++i)
                #pragma unroll
                for (int j = 0; j < TN; ++j)
                    acc[i][j] = fmaf(a[i], b[j], acc[i][j]);
        }
        __syncthreads();
    }
    #pragma unroll
    for (int i = 0; i < TM; ++i) {
        const int grow = row0 + trow * TM + i;
        if (grow < M) {
            float4 v = make_float4(acc[i][0], acc[i][1], acc[i][2], acc[i][3]);
            *(float4*)(C + (size_t)grow * Nc + col0 + tcol * TN) = v;
        }
    }
}

// =====================================================================
// BatchNorm stats
// =====================================================================
__global__ __launch_bounds__(256) void bn_stats_kernel(
    const float* __restrict__ tin, float* __restrict__ sums, int M)
{
    __shared__ float sb[256], qb[256];
    const int col = threadIdx.x & 127;
    const int half = threadIdx.x >> 7;
    const int r0 = blockIdx.x * 128;
    float s = 0.f, q = 0.f;
    #pragma unroll 4
    for (int i = 0; i < 64; ++i) {
        const int r = r0 + i * 2 + half;
        if (r < M) {
            const float v = tin[(size_t)r * 128 + col];
            s += v; q += v * v;
        }
    }
    sb[threadIdx.x] = s; qb[threadIdx.x] = q;
    __syncthreads();
    if (threadIdx.x < 128) {
        s = sb[threadIdx.x] + sb[threadIdx.x + 128];
        q = qb[threadIdx.x] + qb[threadIdx.x + 128];
        unsafeAtomicAdd(&sums[col], s);
        unsafeAtomicAdd(&sums[128 + col], q);
    }
}

__global__ void bn_final_kernel(
    const float* __restrict__ sums, const float* __restrict__ g,
    const float* __restrict__ b, float* __restrict__ scale,
    float* __restrict__ bias, float invN)
{
    const int c = threadIdx.x;
    const float mu = sums[c] * invN;
    const float var = sums[128 + c] * invN - mu * mu;
    const float rs = rsqrtf(var + 1e-5f);
    const float sc = g[c] * rs;
    scale[c] = sc;
    bias[c] = b[c] - mu * sc;
}

// =====================================================================
// CSR build v3 (bucket-binned, block-privatized reservations)
// =====================================================================
__global__ __launch_bounds__(256) void bucket_count_kernel(
    const int* __restrict__ edges, int* __restrict__ bcnt)
{
    const int r = blockIdx.y;
    __shared__ int sh[NBUCK];
    for (int i = threadIdx.x; i < NBUCK; i += 256) sh[i] = 0;
    __syncthreads();
    const int* trg = edges + (size_t)r * 2 * E_EDGES + E_EDGES;
    for (int i = blockIdx.x * 256 + threadIdx.x; i < E_EDGES; i += gridDim.x * 256)
        atomicAdd(&sh[trg[i] >> 7], 1);
    __syncthreads();
    for (int i = threadIdx.x; i < NBUCK; i += 256)
        if (sh[i]) atomicAdd(&bcnt[r * NBUCK + i], sh[i]);
}

__global__ __launch_bounds__(512) void bucket_scan_kernel(
    const int* __restrict__ bcnt, int* __restrict__ bscan,
    int* __restrict__ gbcur, int* __restrict__ rowptr)
{
    const int r = blockIdx.x;
    const int t = threadIdx.x;
    __shared__ int sh[512];
    const int v = (t < NBUCK) ? bcnt[r * NBUCK + t] : 0;
    sh[t] = v;
    __syncthreads();
    for (int off = 1; off < 512; off <<= 1) {
        const int u = (t >= off) ? sh[t - off] : 0;
        __syncthreads();
        sh[t] += u;
        __syncthreads();
    }
    if (t < NBUCK) {
        const int excl = sh[t] - v;
        bscan[r * NBUCK + t] = excl;
        gbcur[(r * NBUCK + t) * 16] = excl;
    }
    if (t == 0) rowptr[(size_t)r * (N_NODES + 1) + N_NODES] = E_EDGES;
}

__global__ __launch_bounds__(256) void bucket_bin_kernel(
    const int* __restrict__ edges, int* __restrict__ gbcur, int2* __restrict__ tmp)
{
    const int r = blockIdx.y;
    const int t = threadIdx.x;
    __shared__ int hist[NBUCK];
    __shared__ int basebuf[NBUCK];
    for (int b = t; b < NBUCK; b += 256) hist[b] = 0;
    __syncthreads();
    const int i0 = blockIdx.x * BIN_CHUNK;
    const int i1 = min(i0 + BIN_CHUNK, E_EDGES);
    const int* srcp = edges + (size_t)r * 2 * E_EDGES;
    const int* trgp = srcp + E_EDGES;
    for (int i = i0 + t; i < i1; i += 256)
        atomicAdd(&hist[trgp[i] >> 7], 1);
    __syncthreads();
    for (int b = t; b < NBUCK; b += 256) {
        const int c = hist[b];
        basebuf[b] = c ? atomicAdd(&gbcur[(r * NBUCK + b) * 16], c) : 0;
        hist[b] = 0;
    }
    __syncthreads();
    for (int i = i0 + t; i < i1; i += 256) {
        const int s = srcp[i], tg = trgp[i];
        const int b = tg >> 7;
        const int pos = basebuf[b] + atomicAdd(&hist[b], 1);
        tmp[(size_t)r * E_EDGES + pos] = make_int2(s, tg);
    }
}

__global__ __launch_bounds__(256) void bucket_finalize_kernel(
    const int2* __restrict__ tmp, const int* __restrict__ bscan,
    int* __restrict__ rowptr, int* __restrict__ srcs)
{
    const int r = blockIdx.y;
    const int b = blockIdx.x;
    const int n0 = b * 128;
    const int nn = min(128, N_NODES - n0);
    const int t = threadIdx.x;
    __shared__ int cnt[128];
    __shared__ int pos128[128];
    if (t < 128) cnt[t] = 0;
    __syncthreads();
    const int e0 = bscan[r * NBUCK + b];
    const int e1 = (b + 1 < NBUCK) ? bscan[r * NBUCK + b + 1] : E_EDGES;
    for (int i = e0 + t; i < e1; i += 256) {
        const int2 p = tmp[(size_t)r * E_EDGES + i];
        atomicAdd(&cnt[p.y - n0], 1);
    }
    __syncthreads();
    if (t < 128) pos128[t] = cnt[t];
    __syncthreads();
    for (int off = 1; off < 128; off <<= 1) {
        int u = 0;
        if (t < 128 && t >= off) u = pos128[t - off];
        __syncthreads();
        if (t < 128) pos128[t] += u;
        __syncthreads();
    }
    if (t < 128) {
        const int excl = pos128[t] - cnt[t];
        if (t < nn) rowptr[(size_t)r * (N_NODES + 1) + n0 + t] = e0 + excl;
        cnt[t] = e0 + excl;
    }
    __syncthreads();
    for (int i = e0 + t; i < e1; i += 256) {
        const int2 p = tmp[(size_t)r * E_EDGES + i];
        const int pos = atomicAdd(&cnt[p.y - n0], 1);
        srcs[(size_t)r * E_EDGES + pos] = p.x;
    }
}

// =====================================================================
// Aggregation (all 3 relations, grid.y = r): one wave per target node;
// 2x-unrolled 8-edge steps; weighted accumulate via v_dot2_f32_f16
// (pack {g0,g1} + {e0,e1} -> fdot2, f32 accumulate).
// Epilogue: residual + leaky, then write h as split bf16 hi/lo.
// =====================================================================
__global__ __launch_bounds__(256) void agg_kernel(
    const int* __restrict__ rowptr_all, const int* __restrict__ srcs_all,
    const f16* __restrict__ gh, const float* __restrict__ el_all,
    const float* __restrict__ er_all, const unsigned* __restrict__ menc,
    const float* __restrict__ x, unsigned short* __restrict__ hhi,
    unsigned short* __restrict__ hlo)
{
    const int r = blockIdx.y;
    const int wid = (blockIdx.x * 256 + threadIdx.x) >> 6;
    const int lane = threadIdx.x & 63;
    if (wid >= N_NODES) return;
    const int* rowptr = rowptr_all + (size_t)r * (N_NODES + 1);
    const int* srcs = srcs_all + (size_t)r * E_EDGES;
    const float* el = el_all + (size_t)r * N_NODES * 8;
    const float* er = er_all + (size_t)r * N_NODES * 8;
    const int rbase = r * 128;
    float Ms = decf(menc[r * 2]) + decf(menc[r * 2 + 1]);
    const float M = Ms > 0.f ? Ms : 0.2f * Ms;
    const int l15 = lane & 15;
    const int sub = lane >> 4;
    const int hd = l15 >> 1;
    const float erv = er[(size_t)wid * 8 + hd];
    const int p0 = rowptr[wid], p1 = rowptr[wid + 1];
    float a[8] = {};
    float den = 0.f;
    for (int base = p0; base < p1; base += 64) {
        int sv = 0;
        if (base + lane < p1) sv = srcs[base + lane];
        const int nn = min(64, p1 - base);
        int j = 0;
        // main: 8 edges per step, 2 gathers in flight, fdot2 accumulate
        for (; j + 8 <= nn; j += 8) {
            const int s0 = __shfl(sv, j + sub, 64);
            const int s1 = __shfl(sv, j + 4 + sub, 64);
            const h8 g0 = *(const h8*)(gh + (size_t)s0 * 384 + rbase + l15 * 8);
            const h8 g1 = *(const h8*)(gh + (size_t)s1 * 384 + rbase + l15 * 8);
            float sc0 = el[(size_t)s0 * 8 + hd] + erv;
            float sc1 = el[(size_t)s1 * 8 + hd] + erv;
            sc0 = sc0 > 0.f ? sc0 : 0.2f * sc0;
            sc1 = sc1 > 0.f ? sc1 : 0.2f * sc1;
            const float e0 = __expf(sc0 - M);
            const float e1 = __expf(sc1 - M);
#if __has_builtin(__builtin_amdgcn_fdot2)
            h2v epk;
            epk[0] = (f16)e0; epk[1] = (f16)e1;
            #pragma unroll
            for (int c = 0; c < 8; ++c) {
                h2v gp;
                gp[0] = g0[c]; gp[1] = g1[c];
                a[c] = __builtin_amdgcn_fdot2(gp, epk, a[c], false);
            }
#else
            #pragma unroll
            for (int c = 0; c < 8; ++c) {
                a[c] = fmaf((float)g0[c], e0, a[c]);
                a[c] = fmaf((float)g1[c], e1, a[c]);
            }
#endif
            den += e0 + e1;
        }
        // tail: predicated 4-edge steps
        for (; j < nn; j += 4) {
            const int jj = j + sub;
            const int s = __shfl(sv, jj, 64);
            float ex = 0.f;
            if (jj < nn) {
                float sc = el[(size_t)s * 8 + hd] + erv;
                sc = sc > 0.f ? sc : 0.2f * sc;
                ex = __expf(sc - M);
            }
            const h8 gv = *(const h8*)(gh + (size_t)s * 384 + rbase + l15 * 8);
            #pragma unroll
            for (int c = 0; c < 8; ++c)
                a[c] = fmaf((float)gv[c], ex, a[c]);
            den += ex;
        }
    }
    #pragma unroll
    for (int c = 0; c < 8; ++c) {
        a[c] += __shfl_xor(a[c], 16, 64);
        a[c] += __shfl_xor(a[c], 32, 64);
    }
    den += __shfl_xor(den, 16, 64);
    den += __shfl_xor(den, 32, 64);
    if (lane < 16) {
        const float inv = 1.f / (den + 1e-16f);
        const size_t o = (size_t)wid * 384 + rbase + l15 * 8;
        const float4 x0 = *(const float4*)(x + o);
        const float4 x1 = *(const float4*)(x + o + 4);
        float hv[8];
        float v;
        v = a[0] * inv; hv[0] = (v > 0.f ? v : 0.01f * v) + x0.x;
        v = a[1] * inv; hv[1] = (v > 0.f ? v : 0.01f * v) + x0.y;
        v = a[2] * inv; hv[2] = (v > 0.f ? v : 0.01f * v) + x0.z;
        v = a[3] * inv; hv[3] = (v > 0.f ? v : 0.01f * v) + x0.w;
        v = a[4] * inv; hv[4] = (v > 0.f ? v : 0.01f * v) + x1.x;
        v = a[5] * inv; hv[5] = (v > 0.f ? v : 0.01f * v) + x1.y;
        v = a[6] * inv; hv[6] = (v > 0.f ? v : 0.01f * v) + x1.z;
        v = a[7] * inv; hv[7] = (v > 0.f ? v : 0.01f * v) + x1.w;
        ushort8 vh, vl;
        unsigned short h_, l_;
        #pragma unroll
        for (int c = 0; c < 8; ++c) {
            split2(hv[c], h_, l_);
            vh[c] = h_; vl[c] = l_;
        }
        *(ushort8*)(hhi + o) = vh;
        *(ushort8*)(hlo + o) = vl;
    }
}

// =====================================================================
extern "C" void kernel_launch(void* const* d_in, const int* in_sizes, int n_in,
                              void* d_out, int out_size, void* d_ws, size_t ws_size,
                              hipStream_t stream) {
    const float* inputs = (const float*)d_in[0];
    const int*   edges  = (const int*)d_in[1];
    const float* W_emb1 = (const float*)d_in[2];
    const float* W_emb2 = (const float*)d_in[3];
    const float* g_emb  = (const float*)d_in[4];
    const float* b_emb  = (const float*)d_in[5];
    const float* Wg     = (const float*)d_in[6];
    const float* al     = (const float*)d_in[7];
    const float* ar     = (const float*)d_in[8];
    const float* W_d1   = (const float*)d_in[9];
    const float* W_d2   = (const float*)d_in[10];
    const float* g_d    = (const float*)d_in[11];
    const float* b_d    = (const float*)d_in[12];
    float* out = (float*)d_out;

    char* base = (char*)d_ws;
    size_t off = 0;
    auto carve = [&](size_t bytes) {
        void* p = base + off;
        off = (off + bytes + 255) & ~(size_t)255;
        return p;
    };
    float* x   = (float*)carve((size_t)N_NODES * D_F * 4);
    unsigned short* hhi = (unsigned short*)carve((size_t)N_NODES * D_F * 2);
    unsigned short* hlo = (unsigned short*)carve((size_t)N_NODES * D_F * 2);
    f16*   tch = (f16*)carve((size_t)N_NODES * D_F * 2);
    float* t1  = (float*)tch;       // ALIAS (MLP phases only)
    int2*  tmp = (int2*)tch;        // ALIAS (CSR build only)
    float* el  = (float*)carve((size_t)R_REL * N_NODES * H_HEADS * 4);
    float* er  = (float*)carve((size_t)R_REL * N_NODES * H_HEADS * 4);
    unsigned short* wg_hi  = (unsigned short*)carve((size_t)L_LAYERS * NC_EXT * 384 * 2);
    unsigned short* wg_lo  = (unsigned short*)carve((size_t)L_LAYERS * NC_EXT * 384 * 2);
    unsigned short* we1_hi = (unsigned short*)carve((size_t)128 * 128 * 2);
    unsigned short* we1_lo = (unsigned short*)carve((size_t)128 * 128 * 2);
    unsigned short* we2_hi = (unsigned short*)carve((size_t)128 * 384 * 2);
    unsigned short* we2_lo = (unsigned short*)carve((size_t)128 * 384 * 2);
    unsigned short* wd1_hi = (unsigned short*)carve((size_t)384 * 128 * 2);
    unsigned short* wd1_lo = (unsigned short*)carve((size_t)384 * 128 * 2);
    float* sums  = (float*)carve(256 * 4);
    float* scale = (float*)carve(128 * 4);
    float* bias  = (float*)carve(128 * 4);
    unsigned* Menc = (unsigned*)carve((size_t)L_LAYERS * 8 * 4);
    int* rowptr = (int*)carve((size_t)R_REL * (N_NODES + 1) * 4);
    int* srcs   = (int*)carve((size_t)R_REL * E_EDGES * 4);
    int* bcnt   = (int*)carve((size_t)R_REL * NBUCK * 4);
    int* bscan  = (int*)carve((size_t)R_REL * NBUCK * 4);
    int* gbcur  = (int*)carve((size_t)R_REL * NBUCK * 16 * 4);

    // ---- weight preps ----
    {
        int tot = L_LAYERS * 384 * 384;
        wg_split_kernel<<<(tot + 255) / 256, 256, 0, stream>>>(Wg, wg_hi, wg_lo);
        tot = L_LAYERS * 128 * 384;
        welr_build_kernel<<<(tot + 255) / 256, 256, 0, stream>>>(Wg, al, ar, wg_hi, wg_lo);
        tot = 128 * 128;
        wsplit_kernel<<<(tot + 255) / 256, 256, 0, stream>>>(W_emb1, we1_hi, we1_lo, 128, 128, tot);
        tot = 128 * 384;
        wsplit_kernel<<<(tot + 255) / 256, 256, 0, stream>>>(W_emb2, we2_hi, we2_lo, 128, 384, tot);
        tot = 384 * 128;
        wsplit_kernel<<<(tot + 255) / 256, 256, 0, stream>>>(W_d1, wd1_hi, wd1_lo, 384, 128, tot);
    }

    // ---- CSR build + Menc reset ----
    hipMemsetAsync(bcnt, 0, (size_t)R_REL * NBUCK * 4, stream);
    hipMemsetAsync(Menc, 0, (size_t)L_LAYERS * 8 * 4, stream);
    {
        dim3 gc(256, R_REL);
        dim3 gbin((E_EDGES + BIN_CHUNK - 1) / BIN_CHUNK, R_REL);
        dim3 gb(NBUCK, R_REL);
        bucket_count_kernel<<<gc, 256, 0, stream>>>(edges, bcnt);
        bucket_scan_kernel<<<R_REL, 512, 0, stream>>>(bcnt, bscan, gbcur, rowptr);
        bucket_bin_kernel<<<gbin, 256, 0, stream>>>(edges, gbcur, tmp);
        bucket_finalize_kernel<<<gb, 256, 0, stream>>>(tmp, bscan, rowptr, srcs);
    }

    const int nrt8 = (NRT + 7) / 8;   // 49

    // ---- Embedding MLP: x = relu(BN(inputs@W_emb1)) @ W_emb2 ----
    {
        mfma_gemm<0, false, false><<<8 * 1 * nrt8, 256, 0, stream>>>(
            inputs, nullptr, nullptr, we1_hi, we1_lo, t1, nullptr,
            N_NODES, IN_F, HID_F, 1, nullptr, nullptr, nullptr, nullptr, nullptr);
        hipMemsetAsync(sums, 0, 256 * 4, stream);
        bn_stats_kernel<<<(N_NODES + 127) / 128, 256, 0, stream>>>(t1, sums, N_NODES);
        bn_final_kernel<<<1, 128, 0, stream>>>(sums, g_emb, b_emb, scale, bias, 1.0f / N_NODES);
        mfma_gemm<0, true, false><<<8 * 3 * nrt8, 256, 0, stream>>>(
            t1, nullptr, nullptr, we2_hi, we2_lo, x, nullptr,
            N_NODES, HID_F, D_F, 3, scale, bias, nullptr, nullptr, nullptr);
    }

    // ---- GAT layers (layer 0 reads x fp32; later layers read pre-split h) ----
    for (int l = 0; l < L_LAYERS; ++l) {
        if (l == 0)
            mfma_gemm<3, false, false><<<8 * 4 * nrt8, 256, 0, stream>>>(
                x, nullptr, nullptr,
                wg_hi + (size_t)l * NC_EXT * 384, wg_lo + (size_t)l * NC_EXT * 384,
                nullptr, tch, N_NODES, D_F, 384, 4, nullptr, nullptr,
                el, er, Menc + l * 8);
        else
            mfma_gemm<3, false, true><<<8 * 4 * nrt8, 256, 0, stream>>>(
                nullptr, hhi, hlo,
                wg_hi + (size_t)l * NC_EXT * 384, wg_lo + (size_t)l * NC_EXT * 384,
                nullptr, tch, N_NODES, D_F, 384, 4, nullptr, nullptr,
                el, er, Menc + l * 8);
        dim3 ga((N_NODES * 64 + 255) / 256, R_REL);
        agg_kernel<<<ga, 256, 0, stream>>>(rowptr, srcs, tch, el, er,
                                           Menc + l * 8, x, hhi, hlo);
    }

    // ---- Decoder MLP: out = relu(BN(h@W_d1)) @ W_d2 ----
    {
        mfma_gemm<0, false, true><<<8 * 1 * nrt8, 256, 0, stream>>>(
            nullptr, hhi, hlo, wd1_hi, wd1_lo, t1, nullptr,
            N_NODES, D_F, HID_F, 1, nullptr, nullptr, nullptr, nullptr, nullptr);
        hipMemsetAsync(sums, 0, 256 * 4, stream);
        bn_stats_kernel<<<(N_NODES + 127) / 128, 256, 0, stream>>>(t1, sums, N_NODES);
        bn_final_kernel<<<1, 128, 0, stream>>>(sums, g_d, b_d, scale, bias, 1.0f / N_NODES);
        dim3 grid((N_NODES + 127) / 128, OUT_F / 64);
        gemm_kernel<true><<<grid, 256, 0, stream>>>(t1, W_d2, out, N_NODES, OUT_F, HID_F, scale, bias);
    }
}

// Round 13
// 889.155 us; speedup vs baseline: 1.1530x; 1.1530x over previous
//
#include <hip/hip_runtime.h>
#include <hip/hip_bf16.h>
#include <cstdint>

#define N_NODES 50000
#define E_EDGES 800000
#define R_REL   3
#define IN_F    128
#define HID_F   128
#define D_F     384
#define H_HEADS 8
#define O_PER   16
#define OUT_F   64
#define L_LAYERS 4
#define NBUCK   391    // ceil(50000/128)
#define M_PAD   50048  // 391*128
#define NRT     391    // row tiles
#define BIN_CHUNK 8192
#define NC_EXT  512    // 3*128 feature cols + 1 block of (48 elr + 80 pad)

typedef __attribute__((ext_vector_type(8))) short short8;
typedef __attribute__((ext_vector_type(8))) unsigned short ushort8;
typedef __attribute__((ext_vector_type(4))) float f32x4;
typedef _Float16 f16;
typedef __attribute__((ext_vector_type(2))) _Float16 h2v;
typedef __attribute__((ext_vector_type(8))) _Float16 h8;

// ---- float atomicMax encoding (monotonic uint mapping) ----
__device__ __forceinline__ unsigned encf(float f) {
    unsigned u = __float_as_uint(f);
    return (u & 0x80000000u) ? ~u : (u | 0x80000000u);
}
__device__ __forceinline__ float decf(unsigned u) {
    return __uint_as_float((u & 0x80000000u) ? (u ^ 0x80000000u) : ~u);
}

__device__ __forceinline__ unsigned short bf16hi(float v) {
    return (unsigned short)(__float_as_uint(v) >> 16);
}

// =====================================================================
// Single-bf16 MFMA GEMM: C = A @ B, block 128x128, BK=64, 4 waves.
// XCD-aware 1D grid: d -> xcd=d&7, j=d>>3, cb=j%NCB, rt=xcd+8*(j/NCB).
// PRESPLIT: A supplied as bf16 (Ahi, stride K). Else fp32 A, truncated
// to bf16 during staging (NORM fuses BN+ReLU first).
// OMODE 0: fp32 C.  OMODE 3: layer-fused tch + el/er + max.
// LDS 32 KB (2 planes of 16 KB) -> ~4 blocks/CU.
// =====================================================================
template<int OMODE, bool NORM, bool PRESPLIT>
__global__ __launch_bounds__(256) void mfma_gemm(
    const float* __restrict__ A, const unsigned short* __restrict__ Ahi,
    const unsigned short* __restrict__ Bhi,
    float* __restrict__ C, f16* __restrict__ Ch, int M, int K, int NcC, int NCB,
    const float* __restrict__ nscale, const float* __restrict__ nbias,
    float* __restrict__ elb, float* __restrict__ erb,
    unsigned* __restrict__ mencb)
{
    const int d = blockIdx.x;
    const int xcd = d & 7;
    const int j = d >> 3;
    const int cb = j % NCB;
    const int rt = xcd + 8 * (j / NCB);
    if (rt >= NRT) return;
    const int col0 = cb * 128;
    const int row0 = rt * 128;

    __shared__ __align__(16) unsigned short sA[128 * 64];
    __shared__ __align__(16) unsigned short sB[128 * 64];

    const int t = threadIdx.x;
    const int lane = t & 63;
    const int w = t >> 6;
    const int wm = (w >> 1) * 64;
    const int wn = (w & 1) * 64;
    const unsigned short* bh = Bhi + (size_t)col0 * K;

    f32x4 acc[4][4] = {};

    for (int k0 = 0; k0 < K; k0 += 64) {
        #pragma unroll
        for (int c = 0; c < 4; ++c) {
            const int lb = c * 256 + t;
            const int arow = lb >> 3;
            const int bkg = (lb & 7) ^ (arow & 7);
            const int grow = row0 + arow;
            if (PRESPLIT) {
                ushort8 vh;
                #pragma unroll
                for (int q = 0; q < 8; ++q) vh[q] = 0;
                if (grow < M)
                    vh = *(const ushort8*)(Ahi + (size_t)grow * K + k0 + bkg * 8);
                *(ushort8*)&sA[lb * 8] = vh;
            } else {
                float4 v0 = make_float4(0.f, 0.f, 0.f, 0.f), v1 = v0;
                if (grow < M) {
                    const float* ap = A + (size_t)grow * K + k0 + bkg * 8;
                    v0 = *(const float4*)ap;
                    v1 = *(const float4*)(ap + 4);
                }
                if (NORM) {
                    const float4 s0 = *(const float4*)(nscale + k0 + bkg * 8);
                    const float4 s1 = *(const float4*)(nscale + k0 + bkg * 8 + 4);
                    const float4 b0 = *(const float4*)(nbias + k0 + bkg * 8);
                    const float4 b1 = *(const float4*)(nbias + k0 + bkg * 8 + 4);
                    v0.x = fmaxf(fmaf(v0.x, s0.x, b0.x), 0.f);
                    v0.y = fmaxf(fmaf(v0.y, s0.y, b0.y), 0.f);
                    v0.z = fmaxf(fmaf(v0.z, s0.z, b0.z), 0.f);
                    v0.w = fmaxf(fmaf(v0.w, s0.w, b0.w), 0.f);
                    v1.x = fmaxf(fmaf(v1.x, s1.x, b1.x), 0.f);
                    v1.y = fmaxf(fmaf(v1.y, s1.y, b1.y), 0.f);
                    v1.z = fmaxf(fmaf(v1.z, s1.z, b1.z), 0.f);
                    v1.w = fmaxf(fmaf(v1.w, s1.w, b1.w), 0.f);
                }
                ushort8 vh;
                vh[0] = bf16hi(v0.x); vh[1] = bf16hi(v0.y);
                vh[2] = bf16hi(v0.z); vh[3] = bf16hi(v0.w);
                vh[4] = bf16hi(v1.x); vh[5] = bf16hi(v1.y);
                vh[6] = bf16hi(v1.z); vh[7] = bf16hi(v1.w);
                *(ushort8*)&sA[lb * 8] = vh;
            }
        }
        #pragma unroll
        for (int c = 0; c < 4; ++c) {
            const int lb = c * 256 + t;
            const int nrow = lb >> 3;
            const int bkg = (lb & 7) ^ (nrow & 7);
            *(ushort8*)&sB[lb * 8] =
                *(const ushort8*)(bh + (size_t)nrow * K + k0 + bkg * 8);
        }
        __syncthreads();
        const int g = lane >> 4;
        const int l15 = lane & 15;
        #pragma unroll
        for (int s = 0; s < 2; ++s) {
            short8 ah[4], bhf[4];
            #pragma unroll
            for (int mf = 0; mf < 4; ++mf) {
                const int rm = wm + mf * 16 + l15;
                ah[mf] = *(const short8*)&sA[rm * 64 + ((s * 4 + g) ^ (rm & 7)) * 8];
            }
            #pragma unroll
            for (int nf = 0; nf < 4; ++nf) {
                const int rn = wn + nf * 16 + l15;
                bhf[nf] = *(const short8*)&sB[rn * 64 + ((s * 4 + g) ^ (rn & 7)) * 8];
            }
            #pragma unroll
            for (int mf = 0; mf < 4; ++mf)
                #pragma unroll
                for (int nf = 0; nf < 4; ++nf)
                    acc[mf][nf] = __builtin_amdgcn_mfma_f32_16x16x32_bf16(
                        ah[mf], bhf[nf], acc[mf][nf], 0, 0, 0);
        }
        __syncthreads();
    }
    const int g4 = lane >> 4;
    const int l15 = lane & 15;
    if (OMODE == 0) {
        #pragma unroll
        for (int mf = 0; mf < 4; ++mf)
            #pragma unroll
            for (int j2 = 0; j2 < 4; ++j2) {
                const int row = row0 + wm + mf * 16 + g4 * 4 + j2;
                if (row < M) {
                    #pragma unroll
                    for (int nf = 0; nf < 4; ++nf)
                        C[(size_t)row * NcC + col0 + wn + nf * 16 + l15] = acc[mf][nf][j2];
                }
            }
    } else if (cb < 3) {
        #pragma unroll
        for (int mf = 0; mf < 4; ++mf)
            #pragma unroll
            for (int j2 = 0; j2 < 4; ++j2) {
                const int row = row0 + wm + mf * 16 + g4 * 4 + j2;
                if (row < M) {
                    #pragma unroll
                    for (int nf = 0; nf < 4; ++nf)
                        Ch[(size_t)row * 384 + col0 + wn + nf * 16 + l15] = (f16)acc[mf][nf][j2];
                }
            }
    } else {
        // elr block: cols c = wn + nf*16 + l15, valid c < 48.
        float mx[3] = {-3.0e38f, -3.0e38f, -3.0e38f};
        if (wn == 0) {
            #pragma unroll
            for (int nf = 0; nf < 3; ++nf) {
                const int c = nf * 16 + l15;
                const int which = (c >> 3) & 1;
                const int hh = c & 7;
                float* dst = (which == 0 ? elb : erb) + (size_t)nf * N_NODES * 8 + hh;
                #pragma unroll
                for (int mf = 0; mf < 4; ++mf)
                    #pragma unroll
                    for (int j2 = 0; j2 < 4; ++j2) {
                        const int row = row0 + wm + mf * 16 + g4 * 4 + j2;
                        if (row < M) {
                            const float v = acc[mf][nf][j2];
                            dst[(size_t)row * 8] = v;
                            mx[nf] = fmaxf(mx[nf], v);
                        }
                    }
            }
        }
        #pragma unroll
        for (int nf = 0; nf < 3; ++nf) {
            mx[nf] = fmaxf(mx[nf], __shfl_xor(mx[nf], 16, 64));
            mx[nf] = fmaxf(mx[nf], __shfl_xor(mx[nf], 32, 64));
        }
        __shared__ float smax[2][48];
        if (wn == 0 && g4 == 0) {
            const int wi = w >> 1;
            #pragma unroll
            for (int nf = 0; nf < 3; ++nf) smax[wi][nf * 16 + l15] = mx[nf];
        }
        __syncthreads();
        if (t < 6) {
            float m_ = -3.0e38f;
            #pragma unroll
            for (int i = 0; i < 8; ++i)
                m_ = fmaxf(m_, fmaxf(smax[0][t * 8 + i], smax[1][t * 8 + i]));
            atomicMax(&mencb[t], encf(m_));
        }
    }
}

// =====================================================================
// Weight preps (bf16 hi plane only)
// =====================================================================
__global__ __launch_bounds__(256) void wsplit_kernel(
    const float* __restrict__ W, unsigned short* __restrict__ hi,
    int K0, int N0, int total)
{
    const int t = blockIdx.x * 256 + threadIdx.x;
    if (t >= total) return;
    const int per = K0 * N0;
    const int m = t / per;
    const int rem = t - m * per;
    const int n = rem / K0;
    const int k = rem - n * K0;
    hi[t] = bf16hi(W[(size_t)m * per + (size_t)k * N0 + n]);
}

__global__ __launch_bounds__(256) void wg_split_kernel(
    const float* __restrict__ Wg, unsigned short* __restrict__ hi)
{
    const int t = blockIdx.x * 256 + threadIdx.x;
    const int total = L_LAYERS * 384 * 384;
    if (t >= total) return;
    const int l = t / (384 * 384);
    const int rem = t - l * 384 * 384;
    const int c = rem / 384;
    const int d = rem - c * 384;
    const int r = c >> 7, n = c & 127;
    hi[((size_t)l * NC_EXT + c) * 384 + d] =
        bf16hi(Wg[(((size_t)(l * 3 + r) * 384 + d) * 128) + n]);
}

__global__ __launch_bounds__(256) void welr_build_kernel(
    const float* __restrict__ Wg, const float* __restrict__ al,
    const float* __restrict__ ar, unsigned short* __restrict__ hi)
{
    const int t = blockIdx.x * 256 + threadIdx.x;
    const int total = L_LAYERS * 128 * 384;
    if (t >= total) return;
    const int l = t / (128 * 384);
    const int rem = t - l * (128 * 384);
    const int c = rem / 384;
    const int d = rem - c * 384;
    float v = 0.f;
    if (c < 48) {
        const int rel = c >> 4, which = (c >> 3) & 1, hh = c & 7;
        const float* wp = Wg + (((size_t)(l * 3 + rel) * 384 + d) * 128 + hh * 16);
        const float* ap = (which ? ar : al) + ((size_t)(l * 3 + rel) * 8 + hh) * 16;
        #pragma unroll
        for (int o = 0; o < 16; ++o) v += wp[o] * ap[o];
    }
    hi[((size_t)l * NC_EXT + 384 + c) * 384 + d] = bf16hi(v);
}

// =====================================================================
// fp32 VALU GEMM (dec2 only)
// =====================================================================
template<bool NORM>
__global__ __launch_bounds__(256) void gemm_kernel(
    const float* __restrict__ A, const float* __restrict__ B, float* __restrict__ C,
    int M, int Nc, int K,
    const float* __restrict__ nscale, const float* __restrict__ nbias)
{
    constexpr int BM = 128, BN = 64, BK = 16, TM = 8, TN = 4;
    __shared__ float As[BK][BM + 4];
    __shared__ float Bs[BK][BN];
    const int t = threadIdx.x;
    const int row0 = blockIdx.x * BM;
    const int col0 = blockIdx.y * BN;
    const int trow = t >> 4;
    const int tcol = t & 15;
    float acc[TM][TN] = {};
    const int arow = t >> 2;
    const int akq = t & 3;
    for (int k0 = 0; k0 < K; k0 += BK) {
        #pragma unroll
        for (int half = 0; half < 2; ++half) {
            const int row = arow + half * 64;
            const int grow = row0 + row;
            float4 v = make_float4(0.f, 0.f, 0.f, 0.f);
            if (grow < M)
                v = *(const float4*)(A + (size_t)grow * K + k0 + akq * 4);
            if (NORM) {
                const float4 sc = *(const float4*)(nscale + k0 + akq * 4);
                const float4 bi = *(const float4*)(nbias + k0 + akq * 4);
                v.x = fmaxf(fmaf(v.x, sc.x, bi.x), 0.f);
                v.y = fmaxf(fmaf(v.y, sc.y, bi.y), 0.f);
                v.z = fmaxf(fmaf(v.z, sc.z, bi.z), 0.f);
                v.w = fmaxf(fmaf(v.w, sc.w, bi.w), 0.f);
            }
            As[akq * 4 + 0][row] = v.x;
            As[akq * 4 + 1][row] = v.y;
            As[akq * 4 + 2][row] = v.z;
            As[akq * 4 + 3][row] = v.w;
        }
        {
            const int krow = t >> 4, c4 = t & 15;
            const float4 v = *(const float4*)(B + (size_t)(k0 + krow) * Nc + col0 + c4 * 4);
            *(float4*)&Bs[krow][c4 * 4] = v;
        }
        __syncthreads();
        #pragma unroll
        for (int k = 0; k < BK; ++k) {
            const float4 a0 = *(const float4*)&As[k][trow * TM];
            const float4 a1 = *(const float4*)&As[k][trow * TM + 4];
            const float4 b4 = *(const float4*)&Bs[k][tcol * TN];
            const float a[8] = {a0.x, a0.y, a0.z, a0.w, a1.x, a1.y, a1.z, a1.w};
            const float b[4] = {b4.x, b4.y, b4.z, b4.w};
            #pragma unroll
            for (int i = 0; i < TM; ++i)
                #pragma unroll
                for (int j = 0; j < TN; ++j)
                    acc[i][j] = fmaf(a[i], b[j], acc[i][j]);
        }
        __syncthreads();
    }
    #pragma unroll
    for (int i = 0; i < TM; ++i) {
        const int grow = row0 + trow * TM + i;
        if (grow < M) {
            float4 v = make_float4(acc[i][0], acc[i][1], acc[i][2], acc[i][3]);
            *(float4*)(C + (size_t)grow * Nc + col0 + tcol * TN) = v;
        }
    }
}

// =====================================================================
// BatchNorm stats
// =====================================================================
__global__ __launch_bounds__(256) void bn_stats_kernel(
    const float* __restrict__ tin, float* __restrict__ sums, int M)
{
    __shared__ float sb[256], qb[256];
    const int col = threadIdx.x & 127;
    const int half = threadIdx.x >> 7;
    const int r0 = blockIdx.x * 128;
    float s = 0.f, q = 0.f;
    #pragma unroll 4
    for (int i = 0; i < 64; ++i) {
        const int r = r0 + i * 2 + half;
        if (r < M) {
            const float v = tin[(size_t)r * 128 + col];
            s += v; q += v * v;
        }
    }
    sb[threadIdx.x] = s; qb[threadIdx.x] = q;
    __syncthreads();
    if (threadIdx.x < 128) {
        s = sb[threadIdx.x] + sb[threadIdx.x + 128];
        q = qb[threadIdx.x] + qb[threadIdx.x + 128];
        unsafeAtomicAdd(&sums[col], s);
        unsafeAtomicAdd(&sums[128 + col], q);
    }
}

__global__ void bn_final_kernel(
    const float* __restrict__ sums, const float* __restrict__ g,
    const float* __restrict__ b, float* __restrict__ scale,
    float* __restrict__ bias, float invN)
{
    const int c = threadIdx.x;
    const float mu = sums[c] * invN;
    const float var = sums[128 + c] * invN - mu * mu;
    const float rs = rsqrtf(var + 1e-5f);
    const float sc = g[c] * rs;
    scale[c] = sc;
    bias[c] = b[c] - mu * sc;
}

// =====================================================================
// CSR build v3 (bucket-binned, block-privatized reservations)
// =====================================================================
__global__ __launch_bounds__(256) void bucket_count_kernel(
    const int* __restrict__ edges, int* __restrict__ bcnt)
{
    const int r = blockIdx.y;
    __shared__ int sh[NBUCK];
    for (int i = threadIdx.x; i < NBUCK; i += 256) sh[i] = 0;
    __syncthreads();
    const int* trg = edges + (size_t)r * 2 * E_EDGES + E_EDGES;
    for (int i = blockIdx.x * 256 + threadIdx.x; i < E_EDGES; i += gridDim.x * 256)
        atomicAdd(&sh[trg[i] >> 7], 1);
    __syncthreads();
    for (int i = threadIdx.x; i < NBUCK; i += 256)
        if (sh[i]) atomicAdd(&bcnt[r * NBUCK + i], sh[i]);
}

__global__ __launch_bounds__(512) void bucket_scan_kernel(
    const int* __restrict__ bcnt, int* __restrict__ bscan,
    int* __restrict__ gbcur, int* __restrict__ rowptr)
{
    const int r = blockIdx.x;
    const int t = threadIdx.x;
    __shared__ int sh[512];
    const int v = (t < NBUCK) ? bcnt[r * NBUCK + t] : 0;
    sh[t] = v;
    __syncthreads();
    for (int off = 1; off < 512; off <<= 1) {
        const int u = (t >= off) ? sh[t - off] : 0;
        __syncthreads();
        sh[t] += u;
        __syncthreads();
    }
    if (t < NBUCK) {
        const int excl = sh[t] - v;
        bscan[r * NBUCK + t] = excl;
        gbcur[(r * NBUCK + t) * 16] = excl;
    }
    if (t == 0) rowptr[(size_t)r * (N_NODES + 1) + N_NODES] = E_EDGES;
}

__global__ __launch_bounds__(256) void bucket_bin_kernel(
    const int* __restrict__ edges, int* __restrict__ gbcur, int2* __restrict__ tmp)
{
    const int r = blockIdx.y;
    const int t = threadIdx.x;
    __shared__ int hist[NBUCK];
    __shared__ int basebuf[NBUCK];
    for (int b = t; b < NBUCK; b += 256) hist[b] = 0;
    __syncthreads();
    const int i0 = blockIdx.x * BIN_CHUNK;
    const int i1 = min(i0 + BIN_CHUNK, E_EDGES);
    const int* srcp = edges + (size_t)r * 2 * E_EDGES;
    const int* trgp = srcp + E_EDGES;
    for (int i = i0 + t; i < i1; i += 256)
        atomicAdd(&hist[trgp[i] >> 7], 1);
    __syncthreads();
    for (int b = t; b < NBUCK; b += 256) {
        const int c = hist[b];
        basebuf[b] = c ? atomicAdd(&gbcur[(r * NBUCK + b) * 16], c) : 0;
        hist[b] = 0;
    }
    __syncthreads();
    for (int i = i0 + t; i < i1; i += 256) {
        const int s = srcp[i], tg = trgp[i];
        const int b = tg >> 7;
        const int pos = basebuf[b] + atomicAdd(&hist[b], 1);
        tmp[(size_t)r * E_EDGES + pos] = make_int2(s, tg);
    }
}

__global__ __launch_bounds__(256) void bucket_finalize_kernel(
    const int2* __restrict__ tmp, const int* __restrict__ bscan,
    int* __restrict__ rowptr, int* __restrict__ srcs)
{
    const int r = blockIdx.y;
    const int b = blockIdx.x;
    const int n0 = b * 128;
    const int nn = min(128, N_NODES - n0);
    const int t = threadIdx.x;
    __shared__ int cnt[128];
    __shared__ int pos128[128];
    if (t < 128) cnt[t] = 0;
    __syncthreads();
    const int e0 = bscan[r * NBUCK + b];
    const int e1 = (b + 1 < NBUCK) ? bscan[r * NBUCK + b + 1] : E_EDGES;
    for (int i = e0 + t; i < e1; i += 256) {
        const int2 p = tmp[(size_t)r * E_EDGES + i];
        atomicAdd(&cnt[p.y - n0], 1);
    }
    __syncthreads();
    if (t < 128) pos128[t] = cnt[t];
    __syncthreads();
    for (int off = 1; off < 128; off <<= 1) {
        int u = 0;
        if (t < 128 && t >= off) u = pos128[t - off];
        __syncthreads();
        if (t < 128) pos128[t] += u;
        __syncthreads();
    }
    if (t < 128) {
        const int excl = pos128[t] - cnt[t];
        if (t < nn) rowptr[(size_t)r * (N_NODES + 1) + n0 + t] = e0 + excl;
        cnt[t] = e0 + excl;
    }
    __syncthreads();
    for (int i = e0 + t; i < e1; i += 256) {
        const int2 p = tmp[(size_t)r * E_EDGES + i];
        const int pos = atomicAdd(&cnt[p.y - n0], 1);
        srcs[(size_t)r * E_EDGES + pos] = p.x;
    }
}

// =====================================================================
// Aggregation (all 3 relations, grid.y = r): one wave per target node;
// 2x-unrolled 8-edge steps with fdot2 accumulate.
// Epilogue: residual + leaky, write h as bf16 (hi plane).
// =====================================================================
__global__ __launch_bounds__(256) void agg_kernel(
    const int* __restrict__ rowptr_all, const int* __restrict__ srcs_all,
    const f16* __restrict__ gh, const float* __restrict__ el_all,
    const float* __restrict__ er_all, const unsigned* __restrict__ menc,
    const float* __restrict__ x, unsigned short* __restrict__ hbf)
{
    const int r = blockIdx.y;
    const int wid = (blockIdx.x * 256 + threadIdx.x) >> 6;
    const int lane = threadIdx.x & 63;
    if (wid >= N_NODES) return;
    const int* rowptr = rowptr_all + (size_t)r * (N_NODES + 1);
    const int* srcs = srcs_all + (size_t)r * E_EDGES;
    const float* el = el_all + (size_t)r * N_NODES * 8;
    const float* er = er_all + (size_t)r * N_NODES * 8;
    const int rbase = r * 128;
    float Ms = decf(menc[r * 2]) + decf(menc[r * 2 + 1]);
    const float M = Ms > 0.f ? Ms : 0.2f * Ms;
    const int l15 = lane & 15;
    const int sub = lane >> 4;
    const int hd = l15 >> 1;
    const float erv = er[(size_t)wid * 8 + hd];
    const int p0 = rowptr[wid], p1 = rowptr[wid + 1];
    float a[8] = {};
    float den = 0.f;
    for (int base = p0; base < p1; base += 64) {
        int sv = 0;
        if (base + lane < p1) sv = srcs[base + lane];
        const int nn = min(64, p1 - base);
        int j = 0;
        for (; j + 8 <= nn; j += 8) {
            const int s0 = __shfl(sv, j + sub, 64);
            const int s1 = __shfl(sv, j + 4 + sub, 64);
            const h8 g0 = *(const h8*)(gh + (size_t)s0 * 384 + rbase + l15 * 8);
            const h8 g1 = *(const h8*)(gh + (size_t)s1 * 384 + rbase + l15 * 8);
            float sc0 = el[(size_t)s0 * 8 + hd] + erv;
            float sc1 = el[(size_t)s1 * 8 + hd] + erv;
            sc0 = sc0 > 0.f ? sc0 : 0.2f * sc0;
            sc1 = sc1 > 0.f ? sc1 : 0.2f * sc1;
            const float e0 = __expf(sc0 - M);
            const float e1 = __expf(sc1 - M);
#if __has_builtin(__builtin_amdgcn_fdot2)
            h2v epk;
            epk[0] = (f16)e0; epk[1] = (f16)e1;
            #pragma unroll
            for (int c = 0; c < 8; ++c) {
                h2v gp;
                gp[0] = g0[c]; gp[1] = g1[c];
                a[c] = __builtin_amdgcn_fdot2(gp, epk, a[c], false);
            }
#else
            #pragma unroll
            for (int c = 0; c < 8; ++c) {
                a[c] = fmaf((float)g0[c], e0, a[c]);
                a[c] = fmaf((float)g1[c], e1, a[c]);
            }
#endif
            den += e0 + e1;
        }
        for (; j < nn; j += 4) {
            const int jj = j + sub;
            const int s = __shfl(sv, jj, 64);
            float ex = 0.f;
            if (jj < nn) {
                float sc = el[(size_t)s * 8 + hd] + erv;
                sc = sc > 0.f ? sc : 0.2f * sc;
                ex = __expf(sc - M);
            }
            const h8 gv = *(const h8*)(gh + (size_t)s * 384 + rbase + l15 * 8);
            #pragma unroll
            for (int c = 0; c < 8; ++c)
                a[c] = fmaf((float)gv[c], ex, a[c]);
            den += ex;
        }
    }
    #pragma unroll
    for (int c = 0; c < 8; ++c) {
        a[c] += __shfl_xor(a[c], 16, 64);
        a[c] += __shfl_xor(a[c], 32, 64);
    }
    den += __shfl_xor(den, 16, 64);
    den += __shfl_xor(den, 32, 64);
    if (lane < 16) {
        const float inv = 1.f / (den + 1e-16f);
        const size_t o = (size_t)wid * 384 + rbase + l15 * 8;
        const float4 x0 = *(const float4*)(x + o);
        const float4 x1 = *(const float4*)(x + o + 4);
        float hv[8];
        float v;
        v = a[0] * inv; hv[0] = (v > 0.f ? v : 0.01f * v) + x0.x;
        v = a[1] * inv; hv[1] = (v > 0.f ? v : 0.01f * v) + x0.y;
        v = a[2] * inv; hv[2] = (v > 0.f ? v : 0.01f * v) + x0.z;
        v = a[3] * inv; hv[3] = (v > 0.f ? v : 0.01f * v) + x0.w;
        v = a[4] * inv; hv[4] = (v > 0.f ? v : 0.01f * v) + x1.x;
        v = a[5] * inv; hv[5] = (v > 0.f ? v : 0.01f * v) + x1.y;
        v = a[6] * inv; hv[6] = (v > 0.f ? v : 0.01f * v) + x1.z;
        v = a[7] * inv; hv[7] = (v > 0.f ? v : 0.01f * v) + x1.w;
        ushort8 vh;
        #pragma unroll
        for (int c = 0; c < 8; ++c) vh[c] = bf16hi(hv[c]);
        *(ushort8*)(hbf + o) = vh;
    }
}

// =====================================================================
extern "C" void kernel_launch(void* const* d_in, const int* in_sizes, int n_in,
                              void* d_out, int out_size, void* d_ws, size_t ws_size,
                              hipStream_t stream) {
    const float* inputs = (const float*)d_in[0];
    const int*   edges  = (const int*)d_in[1];
    const float* W_emb1 = (const float*)d_in[2];
    const float* W_emb2 = (const float*)d_in[3];
    const float* g_emb  = (const float*)d_in[4];
    const float* b_emb  = (const float*)d_in[5];
    const float* Wg     = (const float*)d_in[6];
    const float* al     = (const float*)d_in[7];
    const float* ar     = (const float*)d_in[8];
    const float* W_d1   = (const float*)d_in[9];
    const float* W_d2   = (const float*)d_in[10];
    const float* g_d    = (const float*)d_in[11];
    const float* b_d    = (const float*)d_in[12];
    float* out = (float*)d_out;

    char* base = (char*)d_ws;
    size_t off = 0;
    auto carve = [&](size_t bytes) {
        void* p = base + off;
        off = (off + bytes + 255) & ~(size_t)255;
        return p;
    };
    float* x   = (float*)carve((size_t)N_NODES * D_F * 4);                 // 76.8 MB
    unsigned short* hbf = (unsigned short*)carve((size_t)N_NODES * D_F * 2); // 38.4
    f16*   tch = (f16*)carve((size_t)N_NODES * D_F * 2);                   // 38.4
    float* t1  = (float*)tch;       // ALIAS (MLP phases only)
    int2*  tmp = (int2*)tch;        // ALIAS (CSR build only)
    float* el  = (float*)carve((size_t)R_REL * N_NODES * H_HEADS * 4);
    float* er  = (float*)carve((size_t)R_REL * N_NODES * H_HEADS * 4);
    unsigned short* wg_hi  = (unsigned short*)carve((size_t)L_LAYERS * NC_EXT * 384 * 2);
    unsigned short* we1_hi = (unsigned short*)carve((size_t)128 * 128 * 2);
    unsigned short* we2_hi = (unsigned short*)carve((size_t)128 * 384 * 2);
    unsigned short* wd1_hi = (unsigned short*)carve((size_t)384 * 128 * 2);
    float* sums  = (float*)carve(256 * 4);
    float* scale = (float*)carve(128 * 4);
    float* bias  = (float*)carve(128 * 4);
    unsigned* Menc = (unsigned*)carve((size_t)L_LAYERS * 8 * 4);
    int* rowptr = (int*)carve((size_t)R_REL * (N_NODES + 1) * 4);
    int* srcs   = (int*)carve((size_t)R_REL * E_EDGES * 4);
    int* bcnt   = (int*)carve((size_t)R_REL * NBUCK * 4);
    int* bscan  = (int*)carve((size_t)R_REL * NBUCK * 4);
    int* gbcur  = (int*)carve((size_t)R_REL * NBUCK * 16 * 4);

    // ---- weight preps (bf16 hi only) ----
    {
        int tot = L_LAYERS * 384 * 384;
        wg_split_kernel<<<(tot + 255) / 256, 256, 0, stream>>>(Wg, wg_hi);
        tot = L_LAYERS * 128 * 384;
        welr_build_kernel<<<(tot + 255) / 256, 256, 0, stream>>>(Wg, al, ar, wg_hi);
        tot = 128 * 128;
        wsplit_kernel<<<(tot + 255) / 256, 256, 0, stream>>>(W_emb1, we1_hi, 128, 128, tot);
        tot = 128 * 384;
        wsplit_kernel<<<(tot + 255) / 256, 256, 0, stream>>>(W_emb2, we2_hi, 128, 384, tot);
        tot = 384 * 128;
        wsplit_kernel<<<(tot + 255) / 256, 256, 0, stream>>>(W_d1, wd1_hi, 384, 128, tot);
    }

    // ---- CSR build + Menc reset ----
    hipMemsetAsync(bcnt, 0, (size_t)R_REL * NBUCK * 4, stream);
    hipMemsetAsync(Menc, 0, (size_t)L_LAYERS * 8 * 4, stream);
    {
        dim3 gc(256, R_REL);
        dim3 gbin((E_EDGES + BIN_CHUNK - 1) / BIN_CHUNK, R_REL);
        dim3 gb(NBUCK, R_REL);
        bucket_count_kernel<<<gc, 256, 0, stream>>>(edges, bcnt);
        bucket_scan_kernel<<<R_REL, 512, 0, stream>>>(bcnt, bscan, gbcur, rowptr);
        bucket_bin_kernel<<<gbin, 256, 0, stream>>>(edges, gbcur, tmp);
        bucket_finalize_kernel<<<gb, 256, 0, stream>>>(tmp, bscan, rowptr, srcs);
    }

    const int nrt8 = (NRT + 7) / 8;   // 49

    // ---- Embedding MLP: x = relu(BN(inputs@W_emb1)) @ W_emb2 ----
    {
        mfma_gemm<0, false, false><<<8 * 1 * nrt8, 256, 0, stream>>>(
            inputs, nullptr, we1_hi, t1, nullptr,
            N_NODES, IN_F, HID_F, 1, nullptr, nullptr, nullptr, nullptr, nullptr);
        hipMemsetAsync(sums, 0, 256 * 4, stream);
        bn_stats_kernel<<<(N_NODES + 127) / 128, 256, 0, stream>>>(t1, sums, N_NODES);
        bn_final_kernel<<<1, 128, 0, stream>>>(sums, g_emb, b_emb, scale, bias, 1.0f / N_NODES);
        mfma_gemm<0, true, false><<<8 * 3 * nrt8, 256, 0, stream>>>(
            t1, nullptr, we2_hi, x, nullptr,
            N_NODES, HID_F, D_F, 3, scale, bias, nullptr, nullptr, nullptr);
    }

    // ---- GAT layers (layer 0 reads x fp32; later layers read bf16 h) ----
    for (int l = 0; l < L_LAYERS; ++l) {
        if (l == 0)
            mfma_gemm<3, false, false><<<8 * 4 * nrt8, 256, 0, stream>>>(
                x, nullptr, wg_hi + (size_t)l * NC_EXT * 384,
                nullptr, tch, N_NODES, D_F, 384, 4, nullptr, nullptr,
                el, er, Menc + l * 8);
        else
            mfma_gemm<3, false, true><<<8 * 4 * nrt8, 256, 0, stream>>>(
                nullptr, hbf, wg_hi + (size_t)l * NC_EXT * 384,
                nullptr, tch, N_NODES, D_F, 384, 4, nullptr, nullptr,
                el, er, Menc + l * 8);
        dim3 ga((N_NODES * 64 + 255) / 256, R_REL);
        agg_kernel<<<ga, 256, 0, stream>>>(rowptr, srcs, tch, el, er,
                                           Menc + l * 8, x, hbf);
    }

    // ---- Decoder MLP: out = relu(BN(h@W_d1)) @ W_d2 ----
    {
        mfma_gemm<0, false, true><<<8 * 1 * nrt8, 256, 0, stream>>>(
            nullptr, hbf, wd1_hi, t1, nullptr,
            N_NODES, D_F, HID_F, 1, nullptr, nullptr, nullptr, nullptr, nullptr);
        hipMemsetAsync(sums, 0, 256 * 4, stream);
        bn_stats_kernel<<<(N_NODES + 127) / 128, 256, 0, stream>>>(t1, sums, N_NODES);
        bn_final_kernel<<<1, 128, 0, stream>>>(sums, g_d, b_d, scale, bias, 1.0f / N_NODES);
        dim3 grid((N_NODES + 127) / 128, OUT_F / 64);
        gemm_kernel<true><<<grid, 256, 0, stream>>>(t1, W_d2, out, N_NODES, OUT_F, HID_F, scale, bias);
    }
}

// Round 14
// 842.397 us; speedup vs baseline: 1.2170x; 1.0555x over previous
//
#include <hip/hip_runtime.h>
#include <hip/hip_bf16.h>
#include <cstdint>

#define N_NODES 50000
#define E_EDGES 800000
#define R_REL   3
#define IN_F    128
#define HID_F   128
#define D_F     384
#define H_HEADS 8
#define O_PER   16
#define OUT_F   64
#define L_LAYERS 4
#define NBUCK   391    // ceil(50000/128)
#define M_PAD   50048  // 391*128
#define NRT     391    // row tiles
#define BIN_CHUNK 8192
#define NC_EXT  512    // 3*128 feature cols + 1 block of (48 elr + 80 pad)

typedef __attribute__((ext_vector_type(8))) short short8;
typedef __attribute__((ext_vector_type(8))) unsigned short ushort8;
typedef __attribute__((ext_vector_type(4))) float f32x4;
typedef _Float16 f16;
typedef __attribute__((ext_vector_type(2))) _Float16 h2v;
typedef __attribute__((ext_vector_type(8))) _Float16 h8;

#if __has_builtin(__builtin_amdgcn_global_load_lds)
#define HAVE_GLL 1
typedef __attribute__((address_space(1))) const unsigned int gas_uint;
typedef __attribute__((address_space(3))) unsigned int las_uint;
#else
#define HAVE_GLL 0
#endif

// ---- float atomicMax encoding (monotonic uint mapping) ----
__device__ __forceinline__ unsigned encf(float f) {
    unsigned u = __float_as_uint(f);
    return (u & 0x80000000u) ? ~u : (u | 0x80000000u);
}
__device__ __forceinline__ float decf(unsigned u) {
    return __uint_as_float((u & 0x80000000u) ? (u ^ 0x80000000u) : ~u);
}

__device__ __forceinline__ unsigned short bf16hi(float v) {
    return (unsigned short)(__float_as_uint(v) >> 16);
}

// =====================================================================
// Single-bf16 MFMA GEMM: C = A @ B, block 128x128, BK=64, 4 waves.
// XCD-aware 1D grid: d -> xcd=d&7, j=d>>3, cb=j%NCB, rt=xcd+8*(j/NCB).
// PRESPLIT: A is bf16 (Ahi, stride K); staging via global_load_lds
//   (linear LDS dest + pre-swizzled global src). OOB rows (>=M) read
//   garbage from adjacent workspace -- only feeds never-written C rows.
// Else fp32 A staged via VGPRs (zero-fill + optional NORM=BN+ReLU).
// B always staged via global_load_lds when available.
// OMODE 0: fp32 C.  OMODE 3: layer-fused tch + el/er + max.
// =====================================================================
template<int OMODE, bool NORM, bool PRESPLIT>
__global__ __launch_bounds__(256) void mfma_gemm(
    const float* __restrict__ A, const unsigned short* __restrict__ Ahi,
    const unsigned short* __restrict__ Bhi,
    float* __restrict__ C, f16* __restrict__ Ch, int M, int K, int NcC, int NCB,
    const float* __restrict__ nscale, const float* __restrict__ nbias,
    float* __restrict__ elb, float* __restrict__ erb,
    unsigned* __restrict__ mencb)
{
    const int d = blockIdx.x;
    const int xcd = d & 7;
    const int j = d >> 3;
    const int cb = j % NCB;
    const int rt = xcd + 8 * (j / NCB);
    if (rt >= NRT) return;
    const int col0 = cb * 128;
    const int row0 = rt * 128;

    __shared__ __align__(16) unsigned short sA[128 * 64];
    __shared__ __align__(16) unsigned short sB[128 * 64];

    const int t = threadIdx.x;
    const int lane = t & 63;
    const int w = t >> 6;
    const int wm = (w >> 1) * 64;
    const int wn = (w & 1) * 64;
    const unsigned short* bh = Bhi + (size_t)col0 * K;

    f32x4 acc[4][4] = {};

    for (int k0 = 0; k0 < K; k0 += 64) {
        // ---- stage A ----
        #pragma unroll
        for (int c = 0; c < 4; ++c) {
            const int lb = c * 256 + t;
            const int arow = lb >> 3;
            const int bkg = (lb & 7) ^ (arow & 7);
            const int grow = row0 + arow;
            if (PRESPLIT) {
#if HAVE_GLL
                const int base_lb = c * 256 + (t & 192);  // wave-uniform
                __builtin_amdgcn_global_load_lds(
                    (gas_uint*)(Ahi + (size_t)grow * K + k0 + bkg * 8),
                    (las_uint*)&sA[base_lb * 8], 16, 0, 0);
#else
                ushort8 vh;
                #pragma unroll
                for (int q = 0; q < 8; ++q) vh[q] = 0;
                if (grow < M)
                    vh = *(const ushort8*)(Ahi + (size_t)grow * K + k0 + bkg * 8);
                *(ushort8*)&sA[lb * 8] = vh;
#endif
            } else {
                float4 v0 = make_float4(0.f, 0.f, 0.f, 0.f), v1 = v0;
                if (grow < M) {
                    const float* ap = A + (size_t)grow * K + k0 + bkg * 8;
                    v0 = *(const float4*)ap;
                    v1 = *(const float4*)(ap + 4);
                }
                if (NORM) {
                    const float4 s0 = *(const float4*)(nscale + k0 + bkg * 8);
                    const float4 s1 = *(const float4*)(nscale + k0 + bkg * 8 + 4);
                    const float4 b0 = *(const float4*)(nbias + k0 + bkg * 8);
                    const float4 b1 = *(const float4*)(nbias + k0 + bkg * 8 + 4);
                    v0.x = fmaxf(fmaf(v0.x, s0.x, b0.x), 0.f);
                    v0.y = fmaxf(fmaf(v0.y, s0.y, b0.y), 0.f);
                    v0.z = fmaxf(fmaf(v0.z, s0.z, b0.z), 0.f);
                    v0.w = fmaxf(fmaf(v0.w, s0.w, b0.w), 0.f);
                    v1.x = fmaxf(fmaf(v1.x, s1.x, b1.x), 0.f);
                    v1.y = fmaxf(fmaf(v1.y, s1.y, b1.y), 0.f);
                    v1.z = fmaxf(fmaf(v1.z, s1.z, b1.z), 0.f);
                    v1.w = fmaxf(fmaf(v1.w, s1.w, b1.w), 0.f);
                }
                ushort8 vh;
                vh[0] = bf16hi(v0.x); vh[1] = bf16hi(v0.y);
                vh[2] = bf16hi(v0.z); vh[3] = bf16hi(v0.w);
                vh[4] = bf16hi(v1.x); vh[5] = bf16hi(v1.y);
                vh[6] = bf16hi(v1.z); vh[7] = bf16hi(v1.w);
                *(ushort8*)&sA[lb * 8] = vh;
            }
        }
        // ---- stage B ----
        #pragma unroll
        for (int c = 0; c < 4; ++c) {
            const int lb = c * 256 + t;
            const int nrow = lb >> 3;
            const int bkg = (lb & 7) ^ (nrow & 7);
#if HAVE_GLL
            const int base_lb = c * 256 + (t & 192);
            __builtin_amdgcn_global_load_lds(
                (gas_uint*)(bh + (size_t)nrow * K + k0 + bkg * 8),
                (las_uint*)&sB[base_lb * 8], 16, 0, 0);
#else
            *(ushort8*)&sB[lb * 8] =
                *(const ushort8*)(bh + (size_t)nrow * K + k0 + bkg * 8);
#endif
        }
        __syncthreads();
        const int g = lane >> 4;
        const int l15 = lane & 15;
        #pragma unroll
        for (int s = 0; s < 2; ++s) {
            short8 ah[4], bhf[4];
            #pragma unroll
            for (int mf = 0; mf < 4; ++mf) {
                const int rm = wm + mf * 16 + l15;
                ah[mf] = *(const short8*)&sA[rm * 64 + ((s * 4 + g) ^ (rm & 7)) * 8];
            }
            #pragma unroll
            for (int nf = 0; nf < 4; ++nf) {
                const int rn = wn + nf * 16 + l15;
                bhf[nf] = *(const short8*)&sB[rn * 64 + ((s * 4 + g) ^ (rn & 7)) * 8];
            }
            #pragma unroll
            for (int mf = 0; mf < 4; ++mf)
                #pragma unroll
                for (int nf = 0; nf < 4; ++nf)
                    acc[mf][nf] = __builtin_amdgcn_mfma_f32_16x16x32_bf16(
                        ah[mf], bhf[nf], acc[mf][nf], 0, 0, 0);
        }
        __syncthreads();
    }
    const int g4 = lane >> 4;
    const int l15 = lane & 15;
    if (OMODE == 0) {
        #pragma unroll
        for (int mf = 0; mf < 4; ++mf)
            #pragma unroll
            for (int j2 = 0; j2 < 4; ++j2) {
                const int row = row0 + wm + mf * 16 + g4 * 4 + j2;
                if (row < M) {
                    #pragma unroll
                    for (int nf = 0; nf < 4; ++nf)
                        C[(size_t)row * NcC + col0 + wn + nf * 16 + l15] = acc[mf][nf][j2];
                }
            }
    } else if (cb < 3) {
        #pragma unroll
        for (int mf = 0; mf < 4; ++mf)
            #pragma unroll
            for (int j2 = 0; j2 < 4; ++j2) {
                const int row = row0 + wm + mf * 16 + g4 * 4 + j2;
                if (row < M) {
                    #pragma unroll
                    for (int nf = 0; nf < 4; ++nf)
                        Ch[(size_t)row * 384 + col0 + wn + nf * 16 + l15] = (f16)acc[mf][nf][j2];
                }
            }
    } else {
        // elr block: cols c = wn + nf*16 + l15, valid c < 48.
        float mx[3] = {-3.0e38f, -3.0e38f, -3.0e38f};
        if (wn == 0) {
            #pragma unroll
            for (int nf = 0; nf < 3; ++nf) {
                const int c = nf * 16 + l15;
                const int which = (c >> 3) & 1;
                const int hh = c & 7;
                float* dst = (which == 0 ? elb : erb) + (size_t)nf * N_NODES * 8 + hh;
                #pragma unroll
                for (int mf = 0; mf < 4; ++mf)
                    #pragma unroll
                    for (int j2 = 0; j2 < 4; ++j2) {
                        const int row = row0 + wm + mf * 16 + g4 * 4 + j2;
                        if (row < M) {
                            const float v = acc[mf][nf][j2];
                            dst[(size_t)row * 8] = v;
                            mx[nf] = fmaxf(mx[nf], v);
                        }
                    }
            }
        }
        #pragma unroll
        for (int nf = 0; nf < 3; ++nf) {
            mx[nf] = fmaxf(mx[nf], __shfl_xor(mx[nf], 16, 64));
            mx[nf] = fmaxf(mx[nf], __shfl_xor(mx[nf], 32, 64));
        }
        __shared__ float smax[2][48];
        if (wn == 0 && g4 == 0) {
            const int wi = w >> 1;
            #pragma unroll
            for (int nf = 0; nf < 3; ++nf) smax[wi][nf * 16 + l15] = mx[nf];
        }
        __syncthreads();
        if (t < 6) {
            float m_ = -3.0e38f;
            #pragma unroll
            for (int i = 0; i < 8; ++i)
                m_ = fmaxf(m_, fmaxf(smax[0][t * 8 + i], smax[1][t * 8 + i]));
            atomicMax(&mencb[t], encf(m_));
        }
    }
}

// =====================================================================
// Weight preps (bf16 hi plane only)
// =====================================================================
__global__ __launch_bounds__(256) void wsplit_kernel(
    const float* __restrict__ W, unsigned short* __restrict__ hi,
    int K0, int N0, int total)
{
    const int t = blockIdx.x * 256 + threadIdx.x;
    if (t >= total) return;
    const int per = K0 * N0;
    const int m = t / per;
    const int rem = t - m * per;
    const int n = rem / K0;
    const int k = rem - n * K0;
    hi[t] = bf16hi(W[(size_t)m * per + (size_t)k * N0 + n]);
}

__global__ __launch_bounds__(256) void wg_split_kernel(
    const float* __restrict__ Wg, unsigned short* __restrict__ hi)
{
    const int t = blockIdx.x * 256 + threadIdx.x;
    const int total = L_LAYERS * 384 * 384;
    if (t >= total) return;
    const int l = t / (384 * 384);
    const int rem = t - l * 384 * 384;
    const int c = rem / 384;
    const int d = rem - c * 384;
    const int r = c >> 7, n = c & 127;
    hi[((size_t)l * NC_EXT + c) * 384 + d] =
        bf16hi(Wg[(((size_t)(l * 3 + r) * 384 + d) * 128) + n]);
}

__global__ __launch_bounds__(256) void welr_build_kernel(
    const float* __restrict__ Wg, const float* __restrict__ al,
    const float* __restrict__ ar, unsigned short* __restrict__ hi)
{
    const int t = blockIdx.x * 256 + threadIdx.x;
    const int total = L_LAYERS * 128 * 384;
    if (t >= total) return;
    const int l = t / (128 * 384);
    const int rem = t - l * (128 * 384);
    const int c = rem / 384;
    const int d = rem - c * 384;
    float v = 0.f;
    if (c < 48) {
        const int rel = c >> 4, which = (c >> 3) & 1, hh = c & 7;
        const float* wp = Wg + (((size_t)(l * 3 + rel) * 384 + d) * 128 + hh * 16);
        const float* ap = (which ? ar : al) + ((size_t)(l * 3 + rel) * 8 + hh) * 16;
        #pragma unroll
        for (int o = 0; o < 16; ++o) v += wp[o] * ap[o];
    }
    hi[((size_t)l * NC_EXT + 384 + c) * 384 + d] = bf16hi(v);
}

// =====================================================================
// fp32 VALU GEMM (dec2 only)
// =====================================================================
template<bool NORM>
__global__ __launch_bounds__(256) void gemm_kernel(
    const float* __restrict__ A, const float* __restrict__ B, float* __restrict__ C,
    int M, int Nc, int K,
    const float* __restrict__ nscale, const float* __restrict__ nbias)
{
    constexpr int BM = 128, BN = 64, BK = 16, TM = 8, TN = 4;
    __shared__ float As[BK][BM + 4];
    __shared__ float Bs[BK][BN];
    const int t = threadIdx.x;
    const int row0 = blockIdx.x * BM;
    const int col0 = blockIdx.y * BN;
    const int trow = t >> 4;
    const int tcol = t & 15;
    float acc[TM][TN] = {};
    const int arow = t >> 2;
    const int akq = t & 3;
    for (int k0 = 0; k0 < K; k0 += BK) {
        #pragma unroll
        for (int half = 0; half < 2; ++half) {
            const int row = arow + half * 64;
            const int grow = row0 + row;
            float4 v = make_float4(0.f, 0.f, 0.f, 0.f);
            if (grow < M)
                v = *(const float4*)(A + (size_t)grow * K + k0 + akq * 4);
            if (NORM) {
                const float4 sc = *(const float4*)(nscale + k0 + akq * 4);
                const float4 bi = *(const float4*)(nbias + k0 + akq * 4);
                v.x = fmaxf(fmaf(v.x, sc.x, bi.x), 0.f);
                v.y = fmaxf(fmaf(v.y, sc.y, bi.y), 0.f);
                v.z = fmaxf(fmaf(v.z, sc.z, bi.z), 0.f);
                v.w = fmaxf(fmaf(v.w, sc.w, bi.w), 0.f);
            }
            As[akq * 4 + 0][row] = v.x;
            As[akq * 4 + 1][row] = v.y;
            As[akq * 4 + 2][row] = v.z;
            As[akq * 4 + 3][row] = v.w;
        }
        {
            const int krow = t >> 4, c4 = t & 15;
            const float4 v = *(const float4*)(B + (size_t)(k0 + krow) * Nc + col0 + c4 * 4);
            *(float4*)&Bs[krow][c4 * 4] = v;
        }
        __syncthreads();
        #pragma unroll
        for (int k = 0; k < BK; ++k) {
            const float4 a0 = *(const float4*)&As[k][trow * TM];
            const float4 a1 = *(const float4*)&As[k][trow * TM + 4];
            const float4 b4 = *(const float4*)&Bs[k][tcol * TN];
            const float a[8] = {a0.x, a0.y, a0.z, a0.w, a1.x, a1.y, a1.z, a1.w};
            const float b[4] = {b4.x, b4.y, b4.z, b4.w};
            #pragma unroll
            for (int i = 0; i < TM; ++i)
                #pragma unroll
                for (int j = 0; j < TN; ++j)
                    acc[i][j] = fmaf(a[i], b[j], acc[i][j]);
        }
        __syncthreads();
    }
    #pragma unroll
    for (int i = 0; i < TM; ++i) {
        const int grow = row0 + trow * TM + i;
        if (grow < M) {
            float4 v = make_float4(acc[i][0], acc[i][1], acc[i][2], acc[i][3]);
            *(float4*)(C + (size_t)grow * Nc + col0 + tcol * TN) = v;
        }
    }
}

// =====================================================================
// BatchNorm stats
// =====================================================================
__global__ __launch_bounds__(256) void bn_stats_kernel(
    const float* __restrict__ tin, float* __restrict__ sums, int M)
{
    __shared__ float sb[256], qb[256];
    const int col = threadIdx.x & 127;
    const int half = threadIdx.x >> 7;
    const int r0 = blockIdx.x * 128;
    float s = 0.f, q = 0.f;
    #pragma unroll 4
    for (int i = 0; i < 64; ++i) {
        const int r = r0 + i * 2 + half;
        if (r < M) {
            const float v = tin[(size_t)r * 128 + col];
            s += v; q += v * v;
        }
    }
    sb[threadIdx.x] = s; qb[threadIdx.x] = q;
    __syncthreads();
    if (threadIdx.x < 128) {
        s = sb[threadIdx.x] + sb[threadIdx.x + 128];
        q = qb[threadIdx.x] + qb[threadIdx.x + 128];
        unsafeAtomicAdd(&sums[col], s);
        unsafeAtomicAdd(&sums[128 + col], q);
    }
}

__global__ void bn_final_kernel(
    const float* __restrict__ sums, const float* __restrict__ g,
    const float* __restrict__ b, float* __restrict__ scale,
    float* __restrict__ bias, float invN)
{
    const int c = threadIdx.x;
    const float mu = sums[c] * invN;
    const float var = sums[128 + c] * invN - mu * mu;
    const float rs = rsqrtf(var + 1e-5f);
    const float sc = g[c] * rs;
    scale[c] = sc;
    bias[c] = b[c] - mu * sc;
}

// =====================================================================
// CSR build v3 (bucket-binned, block-privatized reservations)
// =====================================================================
__global__ __launch_bounds__(256) void bucket_count_kernel(
    const int* __restrict__ edges, int* __restrict__ bcnt)
{
    const int r = blockIdx.y;
    __shared__ int sh[NBUCK];
    for (int i = threadIdx.x; i < NBUCK; i += 256) sh[i] = 0;
    __syncthreads();
    const int* trg = edges + (size_t)r * 2 * E_EDGES + E_EDGES;
    for (int i = blockIdx.x * 256 + threadIdx.x; i < E_EDGES; i += gridDim.x * 256)
        atomicAdd(&sh[trg[i] >> 7], 1);
    __syncthreads();
    for (int i = threadIdx.x; i < NBUCK; i += 256)
        if (sh[i]) atomicAdd(&bcnt[r * NBUCK + i], sh[i]);
}

__global__ __launch_bounds__(512) void bucket_scan_kernel(
    const int* __restrict__ bcnt, int* __restrict__ bscan,
    int* __restrict__ gbcur, int* __restrict__ rowptr)
{
    const int r = blockIdx.x;
    const int t = threadIdx.x;
    __shared__ int sh[512];
    const int v = (t < NBUCK) ? bcnt[r * NBUCK + t] : 0;
    sh[t] = v;
    __syncthreads();
    for (int off = 1; off < 512; off <<= 1) {
        const int u = (t >= off) ? sh[t - off] : 0;
        __syncthreads();
        sh[t] += u;
        __syncthreads();
    }
    if (t < NBUCK) {
        const int excl = sh[t] - v;
        bscan[r * NBUCK + t] = excl;
        gbcur[(r * NBUCK + t) * 16] = excl;
    }
    if (t == 0) rowptr[(size_t)r * (N_NODES + 1) + N_NODES] = E_EDGES;
}

__global__ __launch_bounds__(256) void bucket_bin_kernel(
    const int* __restrict__ edges, int* __restrict__ gbcur, int2* __restrict__ tmp)
{
    const int r = blockIdx.y;
    const int t = threadIdx.x;
    __shared__ int hist[NBUCK];
    __shared__ int basebuf[NBUCK];
    for (int b = t; b < NBUCK; b += 256) hist[b] = 0;
    __syncthreads();
    const int i0 = blockIdx.x * BIN_CHUNK;
    const int i1 = min(i0 + BIN_CHUNK, E_EDGES);
    const int* srcp = edges + (size_t)r * 2 * E_EDGES;
    const int* trgp = srcp + E_EDGES;
    for (int i = i0 + t; i < i1; i += 256)
        atomicAdd(&hist[trgp[i] >> 7], 1);
    __syncthreads();
    for (int b = t; b < NBUCK; b += 256) {
        const int c = hist[b];
        basebuf[b] = c ? atomicAdd(&gbcur[(r * NBUCK + b) * 16], c) : 0;
        hist[b] = 0;
    }
    __syncthreads();
    for (int i = i0 + t; i < i1; i += 256) {
        const int s = srcp[i], tg = trgp[i];
        const int b = tg >> 7;
        const int pos = basebuf[b] + atomicAdd(&hist[b], 1);
        tmp[(size_t)r * E_EDGES + pos] = make_int2(s, tg);
    }
}

__global__ __launch_bounds__(256) void bucket_finalize_kernel(
    const int2* __restrict__ tmp, const int* __restrict__ bscan,
    int* __restrict__ rowptr, int* __restrict__ srcs)
{
    const int r = blockIdx.y;
    const int b = blockIdx.x;
    const int n0 = b * 128;
    const int nn = min(128, N_NODES - n0);
    const int t = threadIdx.x;
    __shared__ int cnt[128];
    __shared__ int pos128[128];
    if (t < 128) cnt[t] = 0;
    __syncthreads();
    const int e0 = bscan[r * NBUCK + b];
    const int e1 = (b + 1 < NBUCK) ? bscan[r * NBUCK + b + 1] : E_EDGES;
    for (int i = e0 + t; i < e1; i += 256) {
        const int2 p = tmp[(size_t)r * E_EDGES + i];
        atomicAdd(&cnt[p.y - n0], 1);
    }
    __syncthreads();
    if (t < 128) pos128[t] = cnt[t];
    __syncthreads();
    for (int off = 1; off < 128; off <<= 1) {
        int u = 0;
        if (t < 128 && t >= off) u = pos128[t - off];
        __syncthreads();
        if (t < 128) pos128[t] += u;
        __syncthreads();
    }
    if (t < 128) {
        const int excl = pos128[t] - cnt[t];
        if (t < nn) rowptr[(size_t)r * (N_NODES + 1) + n0 + t] = e0 + excl;
        cnt[t] = e0 + excl;
    }
    __syncthreads();
    for (int i = e0 + t; i < e1; i += 256) {
        const int2 p = tmp[(size_t)r * E_EDGES + i];
        const int pos = atomicAdd(&cnt[p.y - n0], 1);
        srcs[(size_t)r * E_EDGES + pos] = p.x;
    }
}

// =====================================================================
// Aggregation (all 3 relations, grid.y = r): one wave per target node;
// 2x-unrolled 8-edge steps with fdot2 accumulate.
// Epilogue: residual + leaky, write h as bf16 (hi plane).
// =====================================================================
__global__ __launch_bounds__(256) void agg_kernel(
    const int* __restrict__ rowptr_all, const int* __restrict__ srcs_all,
    const f16* __restrict__ gh, const float* __restrict__ el_all,
    const float* __restrict__ er_all, const unsigned* __restrict__ menc,
    const float* __restrict__ x, unsigned short* __restrict__ hbf)
{
    const int r = blockIdx.y;
    const int wid = (blockIdx.x * 256 + threadIdx.x) >> 6;
    const int lane = threadIdx.x & 63;
    if (wid >= N_NODES) return;
    const int* rowptr = rowptr_all + (size_t)r * (N_NODES + 1);
    const int* srcs = srcs_all + (size_t)r * E_EDGES;
    const float* el = el_all + (size_t)r * N_NODES * 8;
    const float* er = er_all + (size_t)r * N_NODES * 8;
    const int rbase = r * 128;
    float Ms = decf(menc[r * 2]) + decf(menc[r * 2 + 1]);
    const float M = Ms > 0.f ? Ms : 0.2f * Ms;
    const int l15 = lane & 15;
    const int sub = lane >> 4;
    const int hd = l15 >> 1;
    const float erv = er[(size_t)wid * 8 + hd];
    const int p0 = rowptr[wid], p1 = rowptr[wid + 1];
    float a[8] = {};
    float den = 0.f;
    for (int base = p0; base < p1; base += 64) {
        int sv = 0;
        if (base + lane < p1) sv = srcs[base + lane];
        const int nn = min(64, p1 - base);
        int j = 0;
        for (; j + 8 <= nn; j += 8) {
            const int s0 = __shfl(sv, j + sub, 64);
            const int s1 = __shfl(sv, j + 4 + sub, 64);
            const h8 g0 = *(const h8*)(gh + (size_t)s0 * 384 + rbase + l15 * 8);
            const h8 g1 = *(const h8*)(gh + (size_t)s1 * 384 + rbase + l15 * 8);
            float sc0 = el[(size_t)s0 * 8 + hd] + erv;
            float sc1 = el[(size_t)s1 * 8 + hd] + erv;
            sc0 = sc0 > 0.f ? sc0 : 0.2f * sc0;
            sc1 = sc1 > 0.f ? sc1 : 0.2f * sc1;
            const float e0 = __expf(sc0 - M);
            const float e1 = __expf(sc1 - M);
#if __has_builtin(__builtin_amdgcn_fdot2)
            h2v epk;
            epk[0] = (f16)e0; epk[1] = (f16)e1;
            #pragma unroll
            for (int c = 0; c < 8; ++c) {
                h2v gp;
                gp[0] = g0[c]; gp[1] = g1[c];
                a[c] = __builtin_amdgcn_fdot2(gp, epk, a[c], false);
            }
#else
            #pragma unroll
            for (int c = 0; c < 8; ++c) {
                a[c] = fmaf((float)g0[c], e0, a[c]);
                a[c] = fmaf((float)g1[c], e1, a[c]);
            }
#endif
            den += e0 + e1;
        }
        for (; j < nn; j += 4) {
            const int jj = j + sub;
            const int s = __shfl(sv, jj, 64);
            float ex = 0.f;
            if (jj < nn) {
                float sc = el[(size_t)s * 8 + hd] + erv;
                sc = sc > 0.f ? sc : 0.2f * sc;
                ex = __expf(sc - M);
            }
            const h8 gv = *(const h8*)(gh + (size_t)s * 384 + rbase + l15 * 8);
            #pragma unroll
            for (int c = 0; c < 8; ++c)
                a[c] = fmaf((float)gv[c], ex, a[c]);
            den += ex;
        }
    }
    #pragma unroll
    for (int c = 0; c < 8; ++c) {
        a[c] += __shfl_xor(a[c], 16, 64);
        a[c] += __shfl_xor(a[c], 32, 64);
    }
    den += __shfl_xor(den, 16, 64);
    den += __shfl_xor(den, 32, 64);
    if (lane < 16) {
        const float inv = 1.f / (den + 1e-16f);
        const size_t o = (size_t)wid * 384 + rbase + l15 * 8;
        const float4 x0 = *(const float4*)(x + o);
        const float4 x1 = *(const float4*)(x + o + 4);
        float hv[8];
        float v;
        v = a[0] * inv; hv[0] = (v > 0.f ? v : 0.01f * v) + x0.x;
        v = a[1] * inv; hv[1] = (v > 0.f ? v : 0.01f * v) + x0.y;
        v = a[2] * inv; hv[2] = (v > 0.f ? v : 0.01f * v) + x0.z;
        v = a[3] * inv; hv[3] = (v > 0.f ? v : 0.01f * v) + x0.w;
        v = a[4] * inv; hv[4] = (v > 0.f ? v : 0.01f * v) + x1.x;
        v = a[5] * inv; hv[5] = (v > 0.f ? v : 0.01f * v) + x1.y;
        v = a[6] * inv; hv[6] = (v > 0.f ? v : 0.01f * v) + x1.z;
        v = a[7] * inv; hv[7] = (v > 0.f ? v : 0.01f * v) + x1.w;
        ushort8 vh;
        #pragma unroll
        for (int c = 0; c < 8; ++c) vh[c] = bf16hi(hv[c]);
        *(ushort8*)(hbf + o) = vh;
    }
}

// =====================================================================
extern "C" void kernel_launch(void* const* d_in, const int* in_sizes, int n_in,
                              void* d_out, int out_size, void* d_ws, size_t ws_size,
                              hipStream_t stream) {
    const float* inputs = (const float*)d_in[0];
    const int*   edges  = (const int*)d_in[1];
    const float* W_emb1 = (const float*)d_in[2];
    const float* W_emb2 = (const float*)d_in[3];
    const float* g_emb  = (const float*)d_in[4];
    const float* b_emb  = (const float*)d_in[5];
    const float* Wg     = (const float*)d_in[6];
    const float* al     = (const float*)d_in[7];
    const float* ar     = (const float*)d_in[8];
    const float* W_d1   = (const float*)d_in[9];
    const float* W_d2   = (const float*)d_in[10];
    const float* g_d    = (const float*)d_in[11];
    const float* b_d    = (const float*)d_in[12];
    float* out = (float*)d_out;

    char* base = (char*)d_ws;
    size_t off = 0;
    auto carve = [&](size_t bytes) {
        void* p = base + off;
        off = (off + bytes + 255) & ~(size_t)255;
        return p;
    };
    float* x   = (float*)carve((size_t)N_NODES * D_F * 4);                 // 76.8 MB
    unsigned short* hbf = (unsigned short*)carve((size_t)N_NODES * D_F * 2); // 38.4
    f16*   tch = (f16*)carve((size_t)N_NODES * D_F * 2);                   // 38.4
    float* t1  = (float*)tch;       // ALIAS (MLP phases only)
    int2*  tmp = (int2*)tch;        // ALIAS (CSR build only)
    float* el  = (float*)carve((size_t)R_REL * N_NODES * H_HEADS * 4);
    float* er  = (float*)carve((size_t)R_REL * N_NODES * H_HEADS * 4);
    unsigned short* wg_hi  = (unsigned short*)carve((size_t)L_LAYERS * NC_EXT * 384 * 2);
    unsigned short* we1_hi = (unsigned short*)carve((size_t)128 * 128 * 2);
    unsigned short* we2_hi = (unsigned short*)carve((size_t)128 * 384 * 2);
    unsigned short* wd1_hi = (unsigned short*)carve((size_t)384 * 128 * 2);
    float* sums  = (float*)carve(256 * 4);
    float* scale = (float*)carve(128 * 4);
    float* bias  = (float*)carve(128 * 4);
    unsigned* Menc = (unsigned*)carve((size_t)L_LAYERS * 8 * 4);
    int* rowptr = (int*)carve((size_t)R_REL * (N_NODES + 1) * 4);
    int* srcs   = (int*)carve((size_t)R_REL * E_EDGES * 4);
    int* bcnt   = (int*)carve((size_t)R_REL * NBUCK * 4);
    int* bscan  = (int*)carve((size_t)R_REL * NBUCK * 4);
    int* gbcur  = (int*)carve((size_t)R_REL * NBUCK * 16 * 4);

    // ---- weight preps (bf16 hi only) ----
    {
        int tot = L_LAYERS * 384 * 384;
        wg_split_kernel<<<(tot + 255) / 256, 256, 0, stream>>>(Wg, wg_hi);
        tot = L_LAYERS * 128 * 384;
        welr_build_kernel<<<(tot + 255) / 256, 256, 0, stream>>>(Wg, al, ar, wg_hi);
        tot = 128 * 128;
        wsplit_kernel<<<(tot + 255) / 256, 256, 0, stream>>>(W_emb1, we1_hi, 128, 128, tot);
        tot = 128 * 384;
        wsplit_kernel<<<(tot + 255) / 256, 256, 0, stream>>>(W_emb2, we2_hi, 128, 384, tot);
        tot = 384 * 128;
        wsplit_kernel<<<(tot + 255) / 256, 256, 0, stream>>>(W_d1, wd1_hi, 384, 128, tot);
    }

    // ---- CSR build + Menc reset ----
    hipMemsetAsync(bcnt, 0, (size_t)R_REL * NBUCK * 4, stream);
    hipMemsetAsync(Menc, 0, (size_t)L_LAYERS * 8 * 4, stream);
    {
        dim3 gc(256, R_REL);
        dim3 gbin((E_EDGES + BIN_CHUNK - 1) / BIN_CHUNK, R_REL);
        dim3 gb(NBUCK, R_REL);
        bucket_count_kernel<<<gc, 256, 0, stream>>>(edges, bcnt);
        bucket_scan_kernel<<<R_REL, 512, 0, stream>>>(bcnt, bscan, gbcur, rowptr);
        bucket_bin_kernel<<<gbin, 256, 0, stream>>>(edges, gbcur, tmp);
        bucket_finalize_kernel<<<gb, 256, 0, stream>>>(tmp, bscan, rowptr, srcs);
    }

    const int nrt8 = (NRT + 7) / 8;   // 49

    // ---- Embedding MLP: x = relu(BN(inputs@W_emb1)) @ W_emb2 ----
    {
        mfma_gemm<0, false, false><<<8 * 1 * nrt8, 256, 0, stream>>>(
            inputs, nullptr, we1_hi, t1, nullptr,
            N_NODES, IN_F, HID_F, 1, nullptr, nullptr, nullptr, nullptr, nullptr);
        hipMemsetAsync(sums, 0, 256 * 4, stream);
        bn_stats_kernel<<<(N_NODES + 127) / 128, 256, 0, stream>>>(t1, sums, N_NODES);
        bn_final_kernel<<<1, 128, 0, stream>>>(sums, g_emb, b_emb, scale, bias, 1.0f / N_NODES);
        mfma_gemm<0, true, false><<<8 * 3 * nrt8, 256, 0, stream>>>(
            t1, nullptr, we2_hi, x, nullptr,
            N_NODES, HID_F, D_F, 3, scale, bias, nullptr, nullptr, nullptr);
    }

    // ---- GAT layers (layer 0 reads x fp32; later layers read bf16 h) ----
    for (int l = 0; l < L_LAYERS; ++l) {
        if (l == 0)
            mfma_gemm<3, false, false><<<8 * 4 * nrt8, 256, 0, stream>>>(
                x, nullptr, wg_hi + (size_t)l * NC_EXT * 384,
                nullptr, tch, N_NODES, D_F, 384, 4, nullptr, nullptr,
                el, er, Menc + l * 8);
        else
            mfma_gemm<3, false, true><<<8 * 4 * nrt8, 256, 0, stream>>>(
                nullptr, hbf, wg_hi + (size_t)l * NC_EXT * 384,
                nullptr, tch, N_NODES, D_F, 384, 4, nullptr, nullptr,
                el, er, Menc + l * 8);
        dim3 ga((N_NODES * 64 + 255) / 256, R_REL);
        agg_kernel<<<ga, 256, 0, stream>>>(rowptr, srcs, tch, el, er,
                                           Menc + l * 8, x, hbf);
    }

    // ---- Decoder MLP: out = relu(BN(h@W_d1)) @ W_d2 ----
    {
        mfma_gemm<0, false, true><<<8 * 1 * nrt8, 256, 0, stream>>>(
            nullptr, hbf, wd1_hi, t1, nullptr,
            N_NODES, D_F, HID_F, 1, nullptr, nullptr, nullptr, nullptr, nullptr);
        hipMemsetAsync(sums, 0, 256 * 4, stream);
        bn_stats_kernel<<<(N_NODES + 127) / 128, 256, 0, stream>>>(t1, sums, N_NODES);
        bn_final_kernel<<<1, 128, 0, stream>>>(sums, g_d, b_d, scale, bias, 1.0f / N_NODES);
        dim3 grid((N_NODES + 127) / 128, OUT_F / 64);
        gemm_kernel<true><<<grid, 256, 0, stream>>>(t1, W_d2, out, N_NODES, OUT_F, HID_F, scale, bias);
    }
}

// Round 15
// 841.842 us; speedup vs baseline: 1.2178x; 1.0007x over previous
//
#include <hip/hip_runtime.h>
#include <hip/hip_bf16.h>
#include <cstdint>

#define N_NODES 50000
#define E_EDGES 800000
#define R_REL   3
#define IN_F    128
#define HID_F   128
#define D_F     384
#define H_HEADS 8
#define O_PER   16
#define OUT_F   64
#define L_LAYERS 4
#define NBUCK   391    // ceil(50000/128)
#define M_PAD   50048  // 391*128
#define NRT     391    // row tiles
#define BIN_CHUNK 8192
#define NC_EXT  512    // 3*128 feature cols + 1 block of (48 elr + 80 pad)

typedef __attribute__((ext_vector_type(8))) short short8;
typedef __attribute__((ext_vector_type(8))) unsigned short ushort8;
typedef __attribute__((ext_vector_type(4))) float f32x4;
typedef _Float16 f16;
typedef __attribute__((ext_vector_type(2))) _Float16 h2v;
typedef __attribute__((ext_vector_type(8))) _Float16 h8;

#if __has_builtin(__builtin_amdgcn_global_load_lds)
#define HAVE_GLL 1
typedef __attribute__((address_space(1))) const unsigned int gas_uint;
typedef __attribute__((address_space(3))) unsigned int las_uint;
#else
#define HAVE_GLL 0
#endif

// ---- float atomicMax encoding (monotonic uint mapping) ----
__device__ __forceinline__ unsigned encf(float f) {
    unsigned u = __float_as_uint(f);
    return (u & 0x80000000u) ? ~u : (u | 0x80000000u);
}
__device__ __forceinline__ float decf(unsigned u) {
    return __uint_as_float((u & 0x80000000u) ? (u ^ 0x80000000u) : ~u);
}

__device__ __forceinline__ unsigned short bf16hi(float v) {
    return (unsigned short)(__float_as_uint(v) >> 16);
}

// =====================================================================
// Single-bf16 MFMA GEMM: C = A @ B, block 128x128, BK=64, 4 waves.
// XCD-aware 1D grid; PRESPLIT A + B staged via global_load_lds.
// OMODE 0: fp32 C.  OMODE 3: layer-fused tch + el/er + max.
// =====================================================================
template<int OMODE, bool NORM, bool PRESPLIT>
__global__ __launch_bounds__(256) void mfma_gemm(
    const float* __restrict__ A, const unsigned short* __restrict__ Ahi,
    const unsigned short* __restrict__ Bhi,
    float* __restrict__ C, f16* __restrict__ Ch, int M, int K, int NcC, int NCB,
    const float* __restrict__ nscale, const float* __restrict__ nbias,
    float* __restrict__ elb, float* __restrict__ erb,
    unsigned* __restrict__ mencb)
{
    const int d = blockIdx.x;
    const int xcd = d & 7;
    const int j = d >> 3;
    const int cb = j % NCB;
    const int rt = xcd + 8 * (j / NCB);
    if (rt >= NRT) return;
    const int col0 = cb * 128;
    const int row0 = rt * 128;

    __shared__ __align__(16) unsigned short sA[128 * 64];
    __shared__ __align__(16) unsigned short sB[128 * 64];

    const int t = threadIdx.x;
    const int lane = t & 63;
    const int w = t >> 6;
    const int wm = (w >> 1) * 64;
    const int wn = (w & 1) * 64;
    const unsigned short* bh = Bhi + (size_t)col0 * K;

    f32x4 acc[4][4] = {};

    for (int k0 = 0; k0 < K; k0 += 64) {
        // ---- stage A ----
        #pragma unroll
        for (int c = 0; c < 4; ++c) {
            const int lb = c * 256 + t;
            const int arow = lb >> 3;
            const int bkg = (lb & 7) ^ (arow & 7);
            const int grow = row0 + arow;
            if (PRESPLIT) {
#if HAVE_GLL
                const int base_lb = c * 256 + (t & 192);  // wave-uniform
                __builtin_amdgcn_global_load_lds(
                    (gas_uint*)(Ahi + (size_t)grow * K + k0 + bkg * 8),
                    (las_uint*)&sA[base_lb * 8], 16, 0, 0);
#else
                ushort8 vh;
                #pragma unroll
                for (int q = 0; q < 8; ++q) vh[q] = 0;
                if (grow < M)
                    vh = *(const ushort8*)(Ahi + (size_t)grow * K + k0 + bkg * 8);
                *(ushort8*)&sA[lb * 8] = vh;
#endif
            } else {
                float4 v0 = make_float4(0.f, 0.f, 0.f, 0.f), v1 = v0;
                if (grow < M) {
                    const float* ap = A + (size_t)grow * K + k0 + bkg * 8;
                    v0 = *(const float4*)ap;
                    v1 = *(const float4*)(ap + 4);
                }
                if (NORM) {
                    const float4 s0 = *(const float4*)(nscale + k0 + bkg * 8);
                    const float4 s1 = *(const float4*)(nscale + k0 + bkg * 8 + 4);
                    const float4 b0 = *(const float4*)(nbias + k0 + bkg * 8);
                    const float4 b1 = *(const float4*)(nbias + k0 + bkg * 8 + 4);
                    v0.x = fmaxf(fmaf(v0.x, s0.x, b0.x), 0.f);
                    v0.y = fmaxf(fmaf(v0.y, s0.y, b0.y), 0.f);
                    v0.z = fmaxf(fmaf(v0.z, s0.z, b0.z), 0.f);
                    v0.w = fmaxf(fmaf(v0.w, s0.w, b0.w), 0.f);
                    v1.x = fmaxf(fmaf(v1.x, s1.x, b1.x), 0.f);
                    v1.y = fmaxf(fmaf(v1.y, s1.y, b1.y), 0.f);
                    v1.z = fmaxf(fmaf(v1.z, s1.z, b1.z), 0.f);
                    v1.w = fmaxf(fmaf(v1.w, s1.w, b1.w), 0.f);
                }
                ushort8 vh;
                vh[0] = bf16hi(v0.x); vh[1] = bf16hi(v0.y);
                vh[2] = bf16hi(v0.z); vh[3] = bf16hi(v0.w);
                vh[4] = bf16hi(v1.x); vh[5] = bf16hi(v1.y);
                vh[6] = bf16hi(v1.z); vh[7] = bf16hi(v1.w);
                *(ushort8*)&sA[lb * 8] = vh;
            }
        }
        // ---- stage B ----
        #pragma unroll
        for (int c = 0; c < 4; ++c) {
            const int lb = c * 256 + t;
            const int nrow = lb >> 3;
            const int bkg = (lb & 7) ^ (nrow & 7);
#if HAVE_GLL
            const int base_lb = c * 256 + (t & 192);
            __builtin_amdgcn_global_load_lds(
                (gas_uint*)(bh + (size_t)nrow * K + k0 + bkg * 8),
                (las_uint*)&sB[base_lb * 8], 16, 0, 0);
#else
            *(ushort8*)&sB[lb * 8] =
                *(const ushort8*)(bh + (size_t)nrow * K + k0 + bkg * 8);
#endif
        }
        __syncthreads();
        const int g = lane >> 4;
        const int l15 = lane & 15;
        #pragma unroll
        for (int s = 0; s < 2; ++s) {
            short8 ah[4], bhf[4];
            #pragma unroll
            for (int mf = 0; mf < 4; ++mf) {
                const int rm = wm + mf * 16 + l15;
                ah[mf] = *(const short8*)&sA[rm * 64 + ((s * 4 + g) ^ (rm & 7)) * 8];
            }
            #pragma unroll
            for (int nf = 0; nf < 4; ++nf) {
                const int rn = wn + nf * 16 + l15;
                bhf[nf] = *(const short8*)&sB[rn * 64 + ((s * 4 + g) ^ (rn & 7)) * 8];
            }
            #pragma unroll
            for (int mf = 0; mf < 4; ++mf)
                #pragma unroll
                for (int nf = 0; nf < 4; ++nf)
                    acc[mf][nf] = __builtin_amdgcn_mfma_f32_16x16x32_bf16(
                        ah[mf], bhf[nf], acc[mf][nf], 0, 0, 0);
        }
        __syncthreads();
    }
    const int g4 = lane >> 4;
    const int l15 = lane & 15;
    if (OMODE == 0) {
        #pragma unroll
        for (int mf = 0; mf < 4; ++mf)
            #pragma unroll
            for (int j2 = 0; j2 < 4; ++j2) {
                const int row = row0 + wm + mf * 16 + g4 * 4 + j2;
                if (row < M) {
                    #pragma unroll
                    for (int nf = 0; nf < 4; ++nf)
                        C[(size_t)row * NcC + col0 + wn + nf * 16 + l15] = acc[mf][nf][j2];
                }
            }
    } else if (cb < 3) {
        #pragma unroll
        for (int mf = 0; mf < 4; ++mf)
            #pragma unroll
            for (int j2 = 0; j2 < 4; ++j2) {
                const int row = row0 + wm + mf * 16 + g4 * 4 + j2;
                if (row < M) {
                    #pragma unroll
                    for (int nf = 0; nf < 4; ++nf)
                        Ch[(size_t)row * 384 + col0 + wn + nf * 16 + l15] = (f16)acc[mf][nf][j2];
                }
            }
    } else {
        // elr block: cols c = wn + nf*16 + l15, valid c < 48.
        float mx[3] = {-3.0e38f, -3.0e38f, -3.0e38f};
        if (wn == 0) {
            #pragma unroll
            for (int nf = 0; nf < 3; ++nf) {
                const int c = nf * 16 + l15;
                const int which = (c >> 3) & 1;
                const int hh = c & 7;
                float* dst = (which == 0 ? elb : erb) + (size_t)nf * N_NODES * 8 + hh;
                #pragma unroll
                for (int mf = 0; mf < 4; ++mf)
                    #pragma unroll
                    for (int j2 = 0; j2 < 4; ++j2) {
                        const int row = row0 + wm + mf * 16 + g4 * 4 + j2;
                        if (row < M) {
                            const float v = acc[mf][nf][j2];
                            dst[(size_t)row * 8] = v;
                            mx[nf] = fmaxf(mx[nf], v);
                        }
                    }
            }
        }
        #pragma unroll
        for (int nf = 0; nf < 3; ++nf) {
            mx[nf] = fmaxf(mx[nf], __shfl_xor(mx[nf], 16, 64));
            mx[nf] = fmaxf(mx[nf], __shfl_xor(mx[nf], 32, 64));
        }
        __shared__ float smax[2][48];
        if (wn == 0 && g4 == 0) {
            const int wi = w >> 1;
            #pragma unroll
            for (int nf = 0; nf < 3; ++nf) smax[wi][nf * 16 + l15] = mx[nf];
        }
        __syncthreads();
        if (t < 6) {
            float m_ = -3.0e38f;
            #pragma unroll
            for (int i = 0; i < 8; ++i)
                m_ = fmaxf(m_, fmaxf(smax[0][t * 8 + i], smax[1][t * 8 + i]));
            atomicMax(&mencb[t], encf(m_));
        }
    }
}

// =====================================================================
// Weight preps (bf16 hi plane only)
// =====================================================================
__global__ __launch_bounds__(256) void wsplit_kernel(
    const float* __restrict__ W, unsigned short* __restrict__ hi,
    int K0, int N0, int total)
{
    const int t = blockIdx.x * 256 + threadIdx.x;
    if (t >= total) return;
    const int per = K0 * N0;
    const int m = t / per;
    const int rem = t - m * per;
    const int n = rem / K0;
    const int k = rem - n * K0;
    hi[t] = bf16hi(W[(size_t)m * per + (size_t)k * N0 + n]);
}

__global__ __launch_bounds__(256) void wg_split_kernel(
    const float* __restrict__ Wg, unsigned short* __restrict__ hi)
{
    const int t = blockIdx.x * 256 + threadIdx.x;
    const int total = L_LAYERS * 384 * 384;
    if (t >= total) return;
    const int l = t / (384 * 384);
    const int rem = t - l * 384 * 384;
    const int c = rem / 384;
    const int d = rem - c * 384;
    const int r = c >> 7, n = c & 127;
    hi[((size_t)l * NC_EXT + c) * 384 + d] =
        bf16hi(Wg[(((size_t)(l * 3 + r) * 384 + d) * 128) + n]);
}

__global__ __launch_bounds__(256) void welr_build_kernel(
    const float* __restrict__ Wg, const float* __restrict__ al,
    const float* __restrict__ ar, unsigned short* __restrict__ hi)
{
    const int t = blockIdx.x * 256 + threadIdx.x;
    const int total = L_LAYERS * 128 * 384;
    if (t >= total) return;
    const int l = t / (128 * 384);
    const int rem = t - l * (128 * 384);
    const int c = rem / 384;
    const int d = rem - c * 384;
    float v = 0.f;
    if (c < 48) {
        const int rel = c >> 4, which = (c >> 3) & 1, hh = c & 7;
        const float* wp = Wg + (((size_t)(l * 3 + rel) * 384 + d) * 128 + hh * 16);
        const float* ap = (which ? ar : al) + ((size_t)(l * 3 + rel) * 8 + hh) * 16;
        #pragma unroll
        for (int o = 0; o < 16; ++o) v += wp[o] * ap[o];
    }
    hi[((size_t)l * NC_EXT + 384 + c) * 384 + d] = bf16hi(v);
}

// =====================================================================
// fp32 VALU GEMM (dec2 only)
// =====================================================================
template<bool NORM>
__global__ __launch_bounds__(256) void gemm_kernel(
    const float* __restrict__ A, const float* __restrict__ B, float* __restrict__ C,
    int M, int Nc, int K,
    const float* __restrict__ nscale, const float* __restrict__ nbias)
{
    constexpr int BM = 128, BN = 64, BK = 16, TM = 8, TN = 4;
    __shared__ float As[BK][BM + 4];
    __shared__ float Bs[BK][BN];
    const int t = threadIdx.x;
    const int row0 = blockIdx.x * BM;
    const int col0 = blockIdx.y * BN;
    const int trow = t >> 4;
    const int tcol = t & 15;
    float acc[TM][TN] = {};
    const int arow = t >> 2;
    const int akq = t & 3;
    for (int k0 = 0; k0 < K; k0 += BK) {
        #pragma unroll
        for (int half = 0; half < 2; ++half) {
            const int row = arow + half * 64;
            const int grow = row0 + row;
            float4 v = make_float4(0.f, 0.f, 0.f, 0.f);
            if (grow < M)
                v = *(const float4*)(A + (size_t)grow * K + k0 + akq * 4);
            if (NORM) {
                const float4 sc = *(const float4*)(nscale + k0 + akq * 4);
                const float4 bi = *(const float4*)(nbias + k0 + akq * 4);
                v.x = fmaxf(fmaf(v.x, sc.x, bi.x), 0.f);
                v.y = fmaxf(fmaf(v.y, sc.y, bi.y), 0.f);
                v.z = fmaxf(fmaf(v.z, sc.z, bi.z), 0.f);
                v.w = fmaxf(fmaf(v.w, sc.w, bi.w), 0.f);
            }
            As[akq * 4 + 0][row] = v.x;
            As[akq * 4 + 1][row] = v.y;
            As[akq * 4 + 2][row] = v.z;
            As[akq * 4 + 3][row] = v.w;
        }
        {
            const int krow = t >> 4, c4 = t & 15;
            const float4 v = *(const float4*)(B + (size_t)(k0 + krow) * Nc + col0 + c4 * 4);
            *(float4*)&Bs[krow][c4 * 4] = v;
        }
        __syncthreads();
        #pragma unroll
        for (int k = 0; k < BK; ++k) {
            const float4 a0 = *(const float4*)&As[k][trow * TM];
            const float4 a1 = *(const float4*)&As[k][trow * TM + 4];
            const float4 b4 = *(const float4*)&Bs[k][tcol * TN];
            const float a[8] = {a0.x, a0.y, a0.z, a0.w, a1.x, a1.y, a1.z, a1.w};
            const float b[4] = {b4.x, b4.y, b4.z, b4.w};
            #pragma unroll
            for (int i = 0; i < TM; ++i)
                #pragma unroll
                for (int j = 0; j < TN; ++j)
                    acc[i][j] = fmaf(a[i], b[j], acc[i][j]);
        }
        __syncthreads();
    }
    #pragma unroll
    for (int i = 0; i < TM; ++i) {
        const int grow = row0 + trow * TM + i;
        if (grow < M) {
            float4 v = make_float4(acc[i][0], acc[i][1], acc[i][2], acc[i][3]);
            *(float4*)(C + (size_t)grow * Nc + col0 + tcol * TN) = v;
        }
    }
}

// =====================================================================
// BatchNorm stats
// =====================================================================
__global__ __launch_bounds__(256) void bn_stats_kernel(
    const float* __restrict__ tin, float* __restrict__ sums, int M)
{
    __shared__ float sb[256], qb[256];
    const int col = threadIdx.x & 127;
    const int half = threadIdx.x >> 7;
    const int r0 = blockIdx.x * 128;
    float s = 0.f, q = 0.f;
    #pragma unroll 4
    for (int i = 0; i < 64; ++i) {
        const int r = r0 + i * 2 + half;
        if (r < M) {
            const float v = tin[(size_t)r * 128 + col];
            s += v; q += v * v;
        }
    }
    sb[threadIdx.x] = s; qb[threadIdx.x] = q;
    __syncthreads();
    if (threadIdx.x < 128) {
        s = sb[threadIdx.x] + sb[threadIdx.x + 128];
        q = qb[threadIdx.x] + qb[threadIdx.x + 128];
        unsafeAtomicAdd(&sums[col], s);
        unsafeAtomicAdd(&sums[128 + col], q);
    }
}

__global__ void bn_final_kernel(
    const float* __restrict__ sums, const float* __restrict__ g,
    const float* __restrict__ b, float* __restrict__ scale,
    float* __restrict__ bias, float invN)
{
    const int c = threadIdx.x;
    const float mu = sums[c] * invN;
    const float var = sums[128 + c] * invN - mu * mu;
    const float rs = rsqrtf(var + 1e-5f);
    const float sc = g[c] * rs;
    scale[c] = sc;
    bias[c] = b[c] - mu * sc;
}

// =====================================================================
// CSR build v3 (bucket-binned, block-privatized reservations)
// =====================================================================
__global__ __launch_bounds__(256) void bucket_count_kernel(
    const int* __restrict__ edges, int* __restrict__ bcnt)
{
    const int r = blockIdx.y;
    __shared__ int sh[NBUCK];
    for (int i = threadIdx.x; i < NBUCK; i += 256) sh[i] = 0;
    __syncthreads();
    const int* trg = edges + (size_t)r * 2 * E_EDGES + E_EDGES;
    for (int i = blockIdx.x * 256 + threadIdx.x; i < E_EDGES; i += gridDim.x * 256)
        atomicAdd(&sh[trg[i] >> 7], 1);
    __syncthreads();
    for (int i = threadIdx.x; i < NBUCK; i += 256)
        if (sh[i]) atomicAdd(&bcnt[r * NBUCK + i], sh[i]);
}

__global__ __launch_bounds__(512) void bucket_scan_kernel(
    const int* __restrict__ bcnt, int* __restrict__ bscan,
    int* __restrict__ gbcur, int* __restrict__ rowptr)
{
    const int r = blockIdx.x;
    const int t = threadIdx.x;
    __shared__ int sh[512];
    const int v = (t < NBUCK) ? bcnt[r * NBUCK + t] : 0;
    sh[t] = v;
    __syncthreads();
    for (int off = 1; off < 512; off <<= 1) {
        const int u = (t >= off) ? sh[t - off] : 0;
        __syncthreads();
        sh[t] += u;
        __syncthreads();
    }
    if (t < NBUCK) {
        const int excl = sh[t] - v;
        bscan[r * NBUCK + t] = excl;
        gbcur[(r * NBUCK + t) * 16] = excl;
    }
    if (t == 0) rowptr[(size_t)r * (N_NODES + 1) + N_NODES] = E_EDGES;
}

__global__ __launch_bounds__(256) void bucket_bin_kernel(
    const int* __restrict__ edges, int* __restrict__ gbcur, int2* __restrict__ tmp)
{
    const int r = blockIdx.y;
    const int t = threadIdx.x;
    __shared__ int hist[NBUCK];
    __shared__ int basebuf[NBUCK];
    for (int b = t; b < NBUCK; b += 256) hist[b] = 0;
    __syncthreads();
    const int i0 = blockIdx.x * BIN_CHUNK;
    const int i1 = min(i0 + BIN_CHUNK, E_EDGES);
    const int* srcp = edges + (size_t)r * 2 * E_EDGES;
    const int* trgp = srcp + E_EDGES;
    for (int i = i0 + t; i < i1; i += 256)
        atomicAdd(&hist[trgp[i] >> 7], 1);
    __syncthreads();
    for (int b = t; b < NBUCK; b += 256) {
        const int c = hist[b];
        basebuf[b] = c ? atomicAdd(&gbcur[(r * NBUCK + b) * 16], c) : 0;
        hist[b] = 0;
    }
    __syncthreads();
    for (int i = i0 + t; i < i1; i += 256) {
        const int s = srcp[i], tg = trgp[i];
        const int b = tg >> 7;
        const int pos = basebuf[b] + atomicAdd(&hist[b], 1);
        tmp[(size_t)r * E_EDGES + pos] = make_int2(s, tg);
    }
}

__global__ __launch_bounds__(256) void bucket_finalize_kernel(
    const int2* __restrict__ tmp, const int* __restrict__ bscan,
    int* __restrict__ rowptr, int* __restrict__ srcs)
{
    const int r = blockIdx.y;
    const int b = blockIdx.x;
    const int n0 = b * 128;
    const int nn = min(128, N_NODES - n0);
    const int t = threadIdx.x;
    __shared__ int cnt[128];
    __shared__ int pos128[128];
    if (t < 128) cnt[t] = 0;
    __syncthreads();
    const int e0 = bscan[r * NBUCK + b];
    const int e1 = (b + 1 < NBUCK) ? bscan[r * NBUCK + b + 1] : E_EDGES;
    for (int i = e0 + t; i < e1; i += 256) {
        const int2 p = tmp[(size_t)r * E_EDGES + i];
        atomicAdd(&cnt[p.y - n0], 1);
    }
    __syncthreads();
    if (t < 128) pos128[t] = cnt[t];
    __syncthreads();
    for (int off = 1; off < 128; off <<= 1) {
        int u = 0;
        if (t < 128 && t >= off) u = pos128[t - off];
        __syncthreads();
        if (t < 128) pos128[t] += u;
        __syncthreads();
    }
    if (t < 128) {
        const int excl = pos128[t] - cnt[t];
        if (t < nn) rowptr[(size_t)r * (N_NODES + 1) + n0 + t] = e0 + excl;
        cnt[t] = e0 + excl;
    }
    __syncthreads();
    for (int i = e0 + t; i < e1; i += 256) {
        const int2 p = tmp[(size_t)r * E_EDGES + i];
        const int pos = atomicAdd(&cnt[p.y - n0], 1);
        srcs[(size_t)r * E_EDGES + pos] = p.x;
    }
}

// =====================================================================
// Aggregation (all 3 relations, grid.y = r): one wave per target node;
// 16-edge main step (4 gathers in flight), 8-edge + 4-edge fallthrough.
// fdot2 accumulate. Epilogue: residual + leaky, write bf16 h.
// =====================================================================
__global__ __launch_bounds__(256) void agg_kernel(
    const int* __restrict__ rowptr_all, const int* __restrict__ srcs_all,
    const f16* __restrict__ gh, const float* __restrict__ el_all,
    const float* __restrict__ er_all, const unsigned* __restrict__ menc,
    const float* __restrict__ x, unsigned short* __restrict__ hbf)
{
    const int r = blockIdx.y;
    const int wid = (blockIdx.x * 256 + threadIdx.x) >> 6;
    const int lane = threadIdx.x & 63;
    if (wid >= N_NODES) return;
    const int* rowptr = rowptr_all + (size_t)r * (N_NODES + 1);
    const int* srcs = srcs_all + (size_t)r * E_EDGES;
    const float* el = el_all + (size_t)r * N_NODES * 8;
    const float* er = er_all + (size_t)r * N_NODES * 8;
    const int rbase = r * 128;
    float Ms = decf(menc[r * 2]) + decf(menc[r * 2 + 1]);
    const float M = Ms > 0.f ? Ms : 0.2f * Ms;
    const int l15 = lane & 15;
    const int sub = lane >> 4;
    const int hd = l15 >> 1;
    const float erv = er[(size_t)wid * 8 + hd];
    const int p0 = rowptr[wid], p1 = rowptr[wid + 1];
    float a[8] = {};
    float den = 0.f;
    for (int base = p0; base < p1; base += 64) {
        int sv = 0;
        if (base + lane < p1) sv = srcs[base + lane];
        const int nn = min(64, p1 - base);
        int j = 0;
        // main: 16 edges per step, 4 independent gathers in flight
        for (; j + 16 <= nn; j += 16) {
            const int s0 = __shfl(sv, j + sub, 64);
            const int s1 = __shfl(sv, j + 4 + sub, 64);
            const int s2 = __shfl(sv, j + 8 + sub, 64);
            const int s3 = __shfl(sv, j + 12 + sub, 64);
            const h8 g0 = *(const h8*)(gh + (size_t)s0 * 384 + rbase + l15 * 8);
            const h8 g1 = *(const h8*)(gh + (size_t)s1 * 384 + rbase + l15 * 8);
            const h8 g2 = *(const h8*)(gh + (size_t)s2 * 384 + rbase + l15 * 8);
            const h8 g3 = *(const h8*)(gh + (size_t)s3 * 384 + rbase + l15 * 8);
            float sc0 = el[(size_t)s0 * 8 + hd] + erv;
            float sc1 = el[(size_t)s1 * 8 + hd] + erv;
            float sc2 = el[(size_t)s2 * 8 + hd] + erv;
            float sc3 = el[(size_t)s3 * 8 + hd] + erv;
            sc0 = sc0 > 0.f ? sc0 : 0.2f * sc0;
            sc1 = sc1 > 0.f ? sc1 : 0.2f * sc1;
            sc2 = sc2 > 0.f ? sc2 : 0.2f * sc2;
            sc3 = sc3 > 0.f ? sc3 : 0.2f * sc3;
            const float e0 = __expf(sc0 - M);
            const float e1 = __expf(sc1 - M);
            const float e2 = __expf(sc2 - M);
            const float e3 = __expf(sc3 - M);
#if __has_builtin(__builtin_amdgcn_fdot2)
            h2v ep01, ep23;
            ep01[0] = (f16)e0; ep01[1] = (f16)e1;
            ep23[0] = (f16)e2; ep23[1] = (f16)e3;
            #pragma unroll
            for (int c = 0; c < 8; ++c) {
                h2v ga_, gb_;
                ga_[0] = g0[c]; ga_[1] = g1[c];
                gb_[0] = g2[c]; gb_[1] = g3[c];
                a[c] = __builtin_amdgcn_fdot2(ga_, ep01, a[c], false);
                a[c] = __builtin_amdgcn_fdot2(gb_, ep23, a[c], false);
            }
#else
            #pragma unroll
            for (int c = 0; c < 8; ++c) {
                a[c] = fmaf((float)g0[c], e0, a[c]);
                a[c] = fmaf((float)g1[c], e1, a[c]);
                a[c] = fmaf((float)g2[c], e2, a[c]);
                a[c] = fmaf((float)g3[c], e3, a[c]);
            }
#endif
            den += (e0 + e1) + (e2 + e3);
        }
        // 8-edge step
        for (; j + 8 <= nn; j += 8) {
            const int s0 = __shfl(sv, j + sub, 64);
            const int s1 = __shfl(sv, j + 4 + sub, 64);
            const h8 g0 = *(const h8*)(gh + (size_t)s0 * 384 + rbase + l15 * 8);
            const h8 g1 = *(const h8*)(gh + (size_t)s1 * 384 + rbase + l15 * 8);
            float sc0 = el[(size_t)s0 * 8 + hd] + erv;
            float sc1 = el[(size_t)s1 * 8 + hd] + erv;
            sc0 = sc0 > 0.f ? sc0 : 0.2f * sc0;
            sc1 = sc1 > 0.f ? sc1 : 0.2f * sc1;
            const float e0 = __expf(sc0 - M);
            const float e1 = __expf(sc1 - M);
#if __has_builtin(__builtin_amdgcn_fdot2)
            h2v epk;
            epk[0] = (f16)e0; epk[1] = (f16)e1;
            #pragma unroll
            for (int c = 0; c < 8; ++c) {
                h2v gp;
                gp[0] = g0[c]; gp[1] = g1[c];
                a[c] = __builtin_amdgcn_fdot2(gp, epk, a[c], false);
            }
#else
            #pragma unroll
            for (int c = 0; c < 8; ++c) {
                a[c] = fmaf((float)g0[c], e0, a[c]);
                a[c] = fmaf((float)g1[c], e1, a[c]);
            }
#endif
            den += e0 + e1;
        }
        // tail: predicated 4-edge steps
        for (; j < nn; j += 4) {
            const int jj = j + sub;
            const int s = __shfl(sv, jj, 64);
            float ex = 0.f;
            if (jj < nn) {
                float sc = el[(size_t)s * 8 + hd] + erv;
                sc = sc > 0.f ? sc : 0.2f * sc;
                ex = __expf(sc - M);
            }
            const h8 gv = *(const h8*)(gh + (size_t)s * 384 + rbase + l15 * 8);
            #pragma unroll
            for (int c = 0; c < 8; ++c)
                a[c] = fmaf((float)gv[c], ex, a[c]);
            den += ex;
        }
    }
    #pragma unroll
    for (int c = 0; c < 8; ++c) {
        a[c] += __shfl_xor(a[c], 16, 64);
        a[c] += __shfl_xor(a[c], 32, 64);
    }
    den += __shfl_xor(den, 16, 64);
    den += __shfl_xor(den, 32, 64);
    if (lane < 16) {
        const float inv = 1.f / (den + 1e-16f);
        const size_t o = (size_t)wid * 384 + rbase + l15 * 8;
        const float4 x0 = *(const float4*)(x + o);
        const float4 x1 = *(const float4*)(x + o + 4);
        float hv[8];
        float v;
        v = a[0] * inv; hv[0] = (v > 0.f ? v : 0.01f * v) + x0.x;
        v = a[1] * inv; hv[1] = (v > 0.f ? v : 0.01f * v) + x0.y;
        v = a[2] * inv; hv[2] = (v > 0.f ? v : 0.01f * v) + x0.z;
        v = a[3] * inv; hv[3] = (v > 0.f ? v : 0.01f * v) + x0.w;
        v = a[4] * inv; hv[4] = (v > 0.f ? v : 0.01f * v) + x1.x;
        v = a[5] * inv; hv[5] = (v > 0.f ? v : 0.01f * v) + x1.y;
        v = a[6] * inv; hv[6] = (v > 0.f ? v : 0.01f * v) + x1.z;
        v = a[7] * inv; hv[7] = (v > 0.f ? v : 0.01f * v) + x1.w;
        ushort8 vh;
        #pragma unroll
        for (int c = 0; c < 8; ++c) vh[c] = bf16hi(hv[c]);
        *(ushort8*)(hbf + o) = vh;
    }
}

// =====================================================================
extern "C" void kernel_launch(void* const* d_in, const int* in_sizes, int n_in,
                              void* d_out, int out_size, void* d_ws, size_t ws_size,
                              hipStream_t stream) {
    const float* inputs = (const float*)d_in[0];
    const int*   edges  = (const int*)d_in[1];
    const float* W_emb1 = (const float*)d_in[2];
    const float* W_emb2 = (const float*)d_in[3];
    const float* g_emb  = (const float*)d_in[4];
    const float* b_emb  = (const float*)d_in[5];
    const float* Wg     = (const float*)d_in[6];
    const float* al     = (const float*)d_in[7];
    const float* ar     = (const float*)d_in[8];
    const float* W_d1   = (const float*)d_in[9];
    const float* W_d2   = (const float*)d_in[10];
    const float* g_d    = (const float*)d_in[11];
    const float* b_d    = (const float*)d_in[12];
    float* out = (float*)d_out;

    char* base = (char*)d_ws;
    size_t off = 0;
    auto carve = [&](size_t bytes) {
        void* p = base + off;
        off = (off + bytes + 255) & ~(size_t)255;
        return p;
    };
    float* x   = (float*)carve((size_t)N_NODES * D_F * 4);                 // 76.8 MB
    unsigned short* hbf = (unsigned short*)carve((size_t)N_NODES * D_F * 2); // 38.4
    f16*   tch = (f16*)carve((size_t)N_NODES * D_F * 2);                   // 38.4
    float* t1  = (float*)tch;       // ALIAS (MLP phases only)
    int2*  tmp = (int2*)tch;        // ALIAS (CSR build only)
    float* el  = (float*)carve((size_t)R_REL * N_NODES * H_HEADS * 4);
    float* er  = (float*)carve((size_t)R_REL * N_NODES * H_HEADS * 4);
    unsigned short* wg_hi  = (unsigned short*)carve((size_t)L_LAYERS * NC_EXT * 384 * 2);
    unsigned short* we1_hi = (unsigned short*)carve((size_t)128 * 128 * 2);
    unsigned short* we2_hi = (unsigned short*)carve((size_t)128 * 384 * 2);
    unsigned short* wd1_hi = (unsigned short*)carve((size_t)384 * 128 * 2);
    float* sums  = (float*)carve(256 * 4);
    float* scale = (float*)carve(128 * 4);
    float* bias  = (float*)carve(128 * 4);
    unsigned* Menc = (unsigned*)carve((size_t)L_LAYERS * 8 * 4);
    int* rowptr = (int*)carve((size_t)R_REL * (N_NODES + 1) * 4);
    int* srcs   = (int*)carve((size_t)R_REL * E_EDGES * 4);
    int* bcnt   = (int*)carve((size_t)R_REL * NBUCK * 4);
    int* bscan  = (int*)carve((size_t)R_REL * NBUCK * 4);
    int* gbcur  = (int*)carve((size_t)R_REL * NBUCK * 16 * 4);

    // ---- weight preps (bf16 hi only) ----
    {
        int tot = L_LAYERS * 384 * 384;
        wg_split_kernel<<<(tot + 255) / 256, 256, 0, stream>>>(Wg, wg_hi);
        tot = L_LAYERS * 128 * 384;
        welr_build_kernel<<<(tot + 255) / 256, 256, 0, stream>>>(Wg, al, ar, wg_hi);
        tot = 128 * 128;
        wsplit_kernel<<<(tot + 255) / 256, 256, 0, stream>>>(W_emb1, we1_hi, 128, 128, tot);
        tot = 128 * 384;
        wsplit_kernel<<<(tot + 255) / 256, 256, 0, stream>>>(W_emb2, we2_hi, 128, 384, tot);
        tot = 384 * 128;
        wsplit_kernel<<<(tot + 255) / 256, 256, 0, stream>>>(W_d1, wd1_hi, 384, 128, tot);
    }

    // ---- CSR build + Menc reset ----
    hipMemsetAsync(bcnt, 0, (size_t)R_REL * NBUCK * 4, stream);
    hipMemsetAsync(Menc, 0, (size_t)L_LAYERS * 8 * 4, stream);
    {
        dim3 gc(256, R_REL);
        dim3 gbin((E_EDGES + BIN_CHUNK - 1) / BIN_CHUNK, R_REL);
        dim3 gb(NBUCK, R_REL);
        bucket_count_kernel<<<gc, 256, 0, stream>>>(edges, bcnt);
        bucket_scan_kernel<<<R_REL, 512, 0, stream>>>(bcnt, bscan, gbcur, rowptr);
        bucket_bin_kernel<<<gbin, 256, 0, stream>>>(edges, gbcur, tmp);
        bucket_finalize_kernel<<<gb, 256, 0, stream>>>(tmp, bscan, rowptr, srcs);
    }

    const int nrt8 = (NRT + 7) / 8;   // 49

    // ---- Embedding MLP: x = relu(BN(inputs@W_emb1)) @ W_emb2 ----
    {
        mfma_gemm<0, false, false><<<8 * 1 * nrt8, 256, 0, stream>>>(
            inputs, nullptr, we1_hi, t1, nullptr,
            N_NODES, IN_F, HID_F, 1, nullptr, nullptr, nullptr, nullptr, nullptr);
        hipMemsetAsync(sums, 0, 256 * 4, stream);
        bn_stats_kernel<<<(N_NODES + 127) / 128, 256, 0, stream>>>(t1, sums, N_NODES);
        bn_final_kernel<<<1, 128, 0, stream>>>(sums, g_emb, b_emb, scale, bias, 1.0f / N_NODES);
        mfma_gemm<0, true, false><<<8 * 3 * nrt8, 256, 0, stream>>>(
            t1, nullptr, we2_hi, x, nullptr,
            N_NODES, HID_F, D_F, 3, scale, bias, nullptr, nullptr, nullptr);
    }

    // ---- GAT layers (layer 0 reads x fp32; later layers read bf16 h) ----
    for (int l = 0; l < L_LAYERS; ++l) {
        if (l == 0)
            mfma_gemm<3, false, false><<<8 * 4 * nrt8, 256, 0, stream>>>(
                x, nullptr, wg_hi + (size_t)l * NC_EXT * 384,
                nullptr, tch, N_NODES, D_F, 384, 4, nullptr, nullptr,
                el, er, Menc + l * 8);
        else
            mfma_gemm<3, false, true><<<8 * 4 * nrt8, 256, 0, stream>>>(
                nullptr, hbf, wg_hi + (size_t)l * NC_EXT * 384,
                nullptr, tch, N_NODES, D_F, 384, 4, nullptr, nullptr,
                el, er, Menc + l * 8);
        dim3 ga((N_NODES * 64 + 255) / 256, R_REL);
        agg_kernel<<<ga, 256, 0, stream>>>(rowptr, srcs, tch, el, er,
                                           Menc + l * 8, x, hbf);
    }

    // ---- Decoder MLP: out = relu(BN(h@W_d1)) @ W_d2 ----
    {
        mfma_gemm<0, false, true><<<8 * 1 * nrt8, 256, 0, stream>>>(
            nullptr, hbf, wd1_hi, t1, nullptr,
            N_NODES, D_F, HID_F, 1, nullptr, nullptr, nullptr, nullptr, nullptr);
        hipMemsetAsync(sums, 0, 256 * 4, stream);
        bn_stats_kernel<<<(N_NODES + 127) / 128, 256, 0, stream>>>(t1, sums, N_NODES);
        bn_final_kernel<<<1, 128, 0, stream>>>(sums, g_d, b_d, scale, bias, 1.0f / N_NODES);
        dim3 grid((N_NODES + 127) / 128, OUT_F / 64);
        gemm_kernel<true><<<grid, 256, 0, stream>>>(t1, W_d2, out, N_NODES, OUT_F, HID_F, scale, bias);
    }
}

// Round 16
// 793.625 us; speedup vs baseline: 1.2918x; 1.0608x over previous
//
#include <hip/hip_runtime.h>
#include <hip/hip_bf16.h>
#include <cstdint>

#define N_NODES 50000
#define E_EDGES 800000
#define R_REL   3
#define IN_F    128
#define HID_F   128
#define D_F     384
#define H_HEADS 8
#define O_PER   16
#define OUT_F   64
#define L_LAYERS 4
#define NBUCK   391    // ceil(50000/128)
#define M_PAD   50048  // 391*128
#define NRT     391    // row tiles
#define BIN_CHUNK 8192
#define NC_EXT  512    // 3*128 feature cols + 1 block of (48 elr + 80 pad)

typedef __attribute__((ext_vector_type(8))) short short8;
typedef __attribute__((ext_vector_type(8))) unsigned short ushort8;
typedef __attribute__((ext_vector_type(4))) float f32x4;
typedef _Float16 f16;
typedef __attribute__((ext_vector_type(2))) _Float16 h2v;
typedef __attribute__((ext_vector_type(8))) _Float16 h8;

#if __has_builtin(__builtin_amdgcn_global_load_lds)
#define HAVE_GLL 1
typedef __attribute__((address_space(1))) const unsigned int gas_uint;
typedef __attribute__((address_space(3))) unsigned int las_uint;
#else
#define HAVE_GLL 0
#endif

// ---- float atomicMax encoding (monotonic uint mapping) ----
__device__ __forceinline__ unsigned encf(float f) {
    unsigned u = __float_as_uint(f);
    return (u & 0x80000000u) ? ~u : (u | 0x80000000u);
}
__device__ __forceinline__ float decf(unsigned u) {
    return __uint_as_float((u & 0x80000000u) ? (u ^ 0x80000000u) : ~u);
}

__device__ __forceinline__ unsigned short bf16hi(float v) {
    return (unsigned short)(__float_as_uint(v) >> 16);
}
__device__ __forceinline__ float bf16f(unsigned short u) {
    return __uint_as_float((unsigned)u << 16);
}

// =====================================================================
// Single-bf16 MFMA GEMM: C = A @ B, block 128x128, BK=64, 4 waves.
// XCD-aware 1D grid; PRESPLIT A + B staged via global_load_lds.
// OMODE 0: fp32 C.  OMODE 1: bf16 Cbf (stride NcC).
// OMODE 3: layer-fused tch(f16) + el/er + max.
// =====================================================================
template<int OMODE, bool NORM, bool PRESPLIT>
__global__ __launch_bounds__(256) void mfma_gemm(
    const float* __restrict__ A, const unsigned short* __restrict__ Ahi,
    const unsigned short* __restrict__ Bhi,
    float* __restrict__ C, unsigned short* __restrict__ Cbf,
    f16* __restrict__ Ch, int M, int K, int NcC, int NCB,
    const float* __restrict__ nscale, const float* __restrict__ nbias,
    float* __restrict__ elb, float* __restrict__ erb,
    unsigned* __restrict__ mencb)
{
    const int d = blockIdx.x;
    const int xcd = d & 7;
    const int j = d >> 3;
    const int cb = j % NCB;
    const int rt = xcd + 8 * (j / NCB);
    if (rt >= NRT) return;
    const int col0 = cb * 128;
    const int row0 = rt * 128;

    __shared__ __align__(16) unsigned short sA[128 * 64];
    __shared__ __align__(16) unsigned short sB[128 * 64];

    const int t = threadIdx.x;
    const int lane = t & 63;
    const int w = t >> 6;
    const int wm = (w >> 1) * 64;
    const int wn = (w & 1) * 64;
    const unsigned short* bh = Bhi + (size_t)col0 * K;

    f32x4 acc[4][4] = {};

    for (int k0 = 0; k0 < K; k0 += 64) {
        // ---- stage A ----
        #pragma unroll
        for (int c = 0; c < 4; ++c) {
            const int lb = c * 256 + t;
            const int arow = lb >> 3;
            const int bkg = (lb & 7) ^ (arow & 7);
            const int grow = row0 + arow;
            if (PRESPLIT) {
#if HAVE_GLL
                const int base_lb = c * 256 + (t & 192);  // wave-uniform
                __builtin_amdgcn_global_load_lds(
                    (gas_uint*)(Ahi + (size_t)grow * K + k0 + bkg * 8),
                    (las_uint*)&sA[base_lb * 8], 16, 0, 0);
#else
                ushort8 vh;
                #pragma unroll
                for (int q = 0; q < 8; ++q) vh[q] = 0;
                if (grow < M)
                    vh = *(const ushort8*)(Ahi + (size_t)grow * K + k0 + bkg * 8);
                *(ushort8*)&sA[lb * 8] = vh;
#endif
            } else {
                float4 v0 = make_float4(0.f, 0.f, 0.f, 0.f), v1 = v0;
                if (grow < M) {
                    const float* ap = A + (size_t)grow * K + k0 + bkg * 8;
                    v0 = *(const float4*)ap;
                    v1 = *(const float4*)(ap + 4);
                }
                if (NORM) {
                    const float4 s0 = *(const float4*)(nscale + k0 + bkg * 8);
                    const float4 s1 = *(const float4*)(nscale + k0 + bkg * 8 + 4);
                    const float4 b0 = *(const float4*)(nbias + k0 + bkg * 8);
                    const float4 b1 = *(const float4*)(nbias + k0 + bkg * 8 + 4);
                    v0.x = fmaxf(fmaf(v0.x, s0.x, b0.x), 0.f);
                    v0.y = fmaxf(fmaf(v0.y, s0.y, b0.y), 0.f);
                    v0.z = fmaxf(fmaf(v0.z, s0.z, b0.z), 0.f);
                    v0.w = fmaxf(fmaf(v0.w, s0.w, b0.w), 0.f);
                    v1.x = fmaxf(fmaf(v1.x, s1.x, b1.x), 0.f);
                    v1.y = fmaxf(fmaf(v1.y, s1.y, b1.y), 0.f);
                    v1.z = fmaxf(fmaf(v1.z, s1.z, b1.z), 0.f);
                    v1.w = fmaxf(fmaf(v1.w, s1.w, b1.w), 0.f);
                }
                ushort8 vh;
                vh[0] = bf16hi(v0.x); vh[1] = bf16hi(v0.y);
                vh[2] = bf16hi(v0.z); vh[3] = bf16hi(v0.w);
                vh[4] = bf16hi(v1.x); vh[5] = bf16hi(v1.y);
                vh[6] = bf16hi(v1.z); vh[7] = bf16hi(v1.w);
                *(ushort8*)&sA[lb * 8] = vh;
            }
        }
        // ---- stage B ----
        #pragma unroll
        for (int c = 0; c < 4; ++c) {
            const int lb = c * 256 + t;
            const int nrow = lb >> 3;
            const int bkg = (lb & 7) ^ (nrow & 7);
#if HAVE_GLL
            const int base_lb = c * 256 + (t & 192);
            __builtin_amdgcn_global_load_lds(
                (gas_uint*)(bh + (size_t)nrow * K + k0 + bkg * 8),
                (las_uint*)&sB[base_lb * 8], 16, 0, 0);
#else
            *(ushort8*)&sB[lb * 8] =
                *(const ushort8*)(bh + (size_t)nrow * K + k0 + bkg * 8);
#endif
        }
        __syncthreads();
        const int g = lane >> 4;
        const int l15 = lane & 15;
        #pragma unroll
        for (int s = 0; s < 2; ++s) {
            short8 ah[4], bhf[4];
            #pragma unroll
            for (int mf = 0; mf < 4; ++mf) {
                const int rm = wm + mf * 16 + l15;
                ah[mf] = *(const short8*)&sA[rm * 64 + ((s * 4 + g) ^ (rm & 7)) * 8];
            }
            #pragma unroll
            for (int nf = 0; nf < 4; ++nf) {
                const int rn = wn + nf * 16 + l15;
                bhf[nf] = *(const short8*)&sB[rn * 64 + ((s * 4 + g) ^ (rn & 7)) * 8];
            }
            #pragma unroll
            for (int mf = 0; mf < 4; ++mf)
                #pragma unroll
                for (int nf = 0; nf < 4; ++nf)
                    acc[mf][nf] = __builtin_amdgcn_mfma_f32_16x16x32_bf16(
                        ah[mf], bhf[nf], acc[mf][nf], 0, 0, 0);
        }
        __syncthreads();
    }
    const int g4 = lane >> 4;
    const int l15 = lane & 15;
    if (OMODE == 0) {
        #pragma unroll
        for (int mf = 0; mf < 4; ++mf)
            #pragma unroll
            for (int j2 = 0; j2 < 4; ++j2) {
                const int row = row0 + wm + mf * 16 + g4 * 4 + j2;
                if (row < M) {
                    #pragma unroll
                    for (int nf = 0; nf < 4; ++nf)
                        C[(size_t)row * NcC + col0 + wn + nf * 16 + l15] = acc[mf][nf][j2];
                }
            }
    } else if (OMODE == 1) {
        #pragma unroll
        for (int mf = 0; mf < 4; ++mf)
            #pragma unroll
            for (int j2 = 0; j2 < 4; ++j2) {
                const int row = row0 + wm + mf * 16 + g4 * 4 + j2;
                if (row < M) {
                    #pragma unroll
                    for (int nf = 0; nf < 4; ++nf)
                        Cbf[(size_t)row * NcC + col0 + wn + nf * 16 + l15] =
                            bf16hi(acc[mf][nf][j2]);
                }
            }
    } else if (cb < 3) {
        #pragma unroll
        for (int mf = 0; mf < 4; ++mf)
            #pragma unroll
            for (int j2 = 0; j2 < 4; ++j2) {
                const int row = row0 + wm + mf * 16 + g4 * 4 + j2;
                if (row < M) {
                    #pragma unroll
                    for (int nf = 0; nf < 4; ++nf)
                        Ch[(size_t)row * 384 + col0 + wn + nf * 16 + l15] = (f16)acc[mf][nf][j2];
                }
            }
    } else {
        // elr block: cols c = wn + nf*16 + l15, valid c < 48.
        float mx[3] = {-3.0e38f, -3.0e38f, -3.0e38f};
        if (wn == 0) {
            #pragma unroll
            for (int nf = 0; nf < 3; ++nf) {
                const int c = nf * 16 + l15;
                const int which = (c >> 3) & 1;
                const int hh = c & 7;
                float* dst = (which == 0 ? elb : erb) + (size_t)nf * N_NODES * 8 + hh;
                #pragma unroll
                for (int mf = 0; mf < 4; ++mf)
                    #pragma unroll
                    for (int j2 = 0; j2 < 4; ++j2) {
                        const int row = row0 + wm + mf * 16 + g4 * 4 + j2;
                        if (row < M) {
                            const float v = acc[mf][nf][j2];
                            dst[(size_t)row * 8] = v;
                            mx[nf] = fmaxf(mx[nf], v);
                        }
                    }
            }
        }
        #pragma unroll
        for (int nf = 0; nf < 3; ++nf) {
            mx[nf] = fmaxf(mx[nf], __shfl_xor(mx[nf], 16, 64));
            mx[nf] = fmaxf(mx[nf], __shfl_xor(mx[nf], 32, 64));
        }
        __shared__ float smax[2][48];
        if (wn == 0 && g4 == 0) {
            const int wi = w >> 1;
            #pragma unroll
            for (int nf = 0; nf < 3; ++nf) smax[wi][nf * 16 + l15] = mx[nf];
        }
        __syncthreads();
        if (t < 6) {
            float m_ = -3.0e38f;
            #pragma unroll
            for (int i = 0; i < 8; ++i)
                m_ = fmaxf(m_, fmaxf(smax[0][t * 8 + i], smax[1][t * 8 + i]));
            atomicMax(&mencb[t], encf(m_));
        }
    }
}

// =====================================================================
// Weight preps (bf16 hi plane only)
// =====================================================================
__global__ __launch_bounds__(256) void wsplit_kernel(
    const float* __restrict__ W, unsigned short* __restrict__ hi,
    int K0, int N0, int total)
{
    const int t = blockIdx.x * 256 + threadIdx.x;
    if (t >= total) return;
    const int per = K0 * N0;
    const int m = t / per;
    const int rem = t - m * per;
    const int n = rem / K0;
    const int k = rem - n * K0;
    hi[t] = bf16hi(W[(size_t)m * per + (size_t)k * N0 + n]);
}

__global__ __launch_bounds__(256) void wg_split_kernel(
    const float* __restrict__ Wg, unsigned short* __restrict__ hi)
{
    const int t = blockIdx.x * 256 + threadIdx.x;
    const int total = L_LAYERS * 384 * 384;
    if (t >= total) return;
    const int l = t / (384 * 384);
    const int rem = t - l * 384 * 384;
    const int c = rem / 384;
    const int d = rem - c * 384;
    const int r = c >> 7, n = c & 127;
    hi[((size_t)l * NC_EXT + c) * 384 + d] =
        bf16hi(Wg[(((size_t)(l * 3 + r) * 384 + d) * 128) + n]);
}

__global__ __launch_bounds__(256) void welr_build_kernel(
    const float* __restrict__ Wg, const float* __restrict__ al,
    const float* __restrict__ ar, unsigned short* __restrict__ hi)
{
    const int t = blockIdx.x * 256 + threadIdx.x;
    const int total = L_LAYERS * 128 * 384;
    if (t >= total) return;
    const int l = t / (128 * 384);
    const int rem = t - l * (128 * 384);
    const int c = rem / 384;
    const int d = rem - c * 384;
    float v = 0.f;
    if (c < 48) {
        const int rel = c >> 4, which = (c >> 3) & 1, hh = c & 7;
        const float* wp = Wg + (((size_t)(l * 3 + rel) * 384 + d) * 128 + hh * 16);
        const float* ap = (which ? ar : al) + ((size_t)(l * 3 + rel) * 8 + hh) * 16;
        #pragma unroll
        for (int o = 0; o < 16; ++o) v += wp[o] * ap[o];
    }
    hi[((size_t)l * NC_EXT + 384 + c) * 384 + d] = bf16hi(v);
}

// =====================================================================
// fp32 VALU GEMM (dec2 only)
// =====================================================================
template<bool NORM>
__global__ __launch_bounds__(256) void gemm_kernel(
    const float* __restrict__ A, const float* __restrict__ B, float* __restrict__ C,
    int M, int Nc, int K,
    const float* __restrict__ nscale, const float* __restrict__ nbias)
{
    constexpr int BM = 128, BN = 64, BK = 16, TM = 8, TN = 4;
    __shared__ float As[BK][BM + 4];
    __shared__ float Bs[BK][BN];
    const int t = threadIdx.x;
    const int row0 = blockIdx.x * BM;
    const int col0 = blockIdx.y * BN;
    const int trow = t >> 4;
    const int tcol = t & 15;
    float acc[TM][TN] = {};
    const int arow = t >> 2;
    const int akq = t & 3;
    for (int k0 = 0; k0 < K; k0 += BK) {
        #pragma unroll
        for (int half = 0; half < 2; ++half) {
            const int row = arow + half * 64;
            const int grow = row0 + row;
            float4 v = make_float4(0.f, 0.f, 0.f, 0.f);
            if (grow < M)
                v = *(const float4*)(A + (size_t)grow * K + k0 + akq * 4);
            if (NORM) {
                const float4 sc = *(const float4*)(nscale + k0 + akq * 4);
                const float4 bi = *(const float4*)(nbias + k0 + akq * 4);
                v.x = fmaxf(fmaf(v.x, sc.x, bi.x), 0.f);
                v.y = fmaxf(fmaf(v.y, sc.y, bi.y), 0.f);
                v.z = fmaxf(fmaf(v.z, sc.z, bi.z), 0.f);
                v.w = fmaxf(fmaf(v.w, sc.w, bi.w), 0.f);
            }
            As[akq * 4 + 0][row] = v.x;
            As[akq * 4 + 1][row] = v.y;
            As[akq * 4 + 2][row] = v.z;
            As[akq * 4 + 3][row] = v.w;
        }
        {
            const int krow = t >> 4, c4 = t & 15;
            const float4 v = *(const float4*)(B + (size_t)(k0 + krow) * Nc + col0 + c4 * 4);
            *(float4*)&Bs[krow][c4 * 4] = v;
        }
        __syncthreads();
        #pragma unroll
        for (int k = 0; k < BK; ++k) {
            const float4 a0 = *(const float4*)&As[k][trow * TM];
            const float4 a1 = *(const float4*)&As[k][trow * TM + 4];
            const float4 b4 = *(const float4*)&Bs[k][tcol * TN];
            const float a[8] = {a0.x, a0.y, a0.z, a0.w, a1.x, a1.y, a1.z, a1.w};
            const float b[4] = {b4.x, b4.y, b4.z, b4.w};
            #pragma unroll
            for (int i = 0; i < TM; ++i)
                #pragma unroll
                for (int j = 0; j < TN; ++j)
                    acc[i][j] = fmaf(a[i], b[j], acc[i][j]);
        }
        __syncthreads();
    }
    #pragma unroll
    for (int i = 0; i < TM; ++i) {
        const int grow = row0 + trow * TM + i;
        if (grow < M) {
            float4 v = make_float4(acc[i][0], acc[i][1], acc[i][2], acc[i][3]);
            *(float4*)(C + (size_t)grow * Nc + col0 + tcol * TN) = v;
        }
    }
}

// =====================================================================
// BatchNorm stats
// =====================================================================
__global__ __launch_bounds__(256) void bn_stats_kernel(
    const float* __restrict__ tin, float* __restrict__ sums, int M)
{
    __shared__ float sb[256], qb[256];
    const int col = threadIdx.x & 127;
    const int half = threadIdx.x >> 7;
    const int r0 = blockIdx.x * 128;
    float s = 0.f, q = 0.f;
    #pragma unroll 4
    for (int i = 0; i < 64; ++i) {
        const int r = r0 + i * 2 + half;
        if (r < M) {
            const float v = tin[(size_t)r * 128 + col];
            s += v; q += v * v;
        }
    }
    sb[threadIdx.x] = s; qb[threadIdx.x] = q;
    __syncthreads();
    if (threadIdx.x < 128) {
        s = sb[threadIdx.x] + sb[threadIdx.x + 128];
        q = qb[threadIdx.x] + qb[threadIdx.x + 128];
        unsafeAtomicAdd(&sums[col], s);
        unsafeAtomicAdd(&sums[128 + col], q);
    }
}

__global__ void bn_final_kernel(
    const float* __restrict__ sums, const float* __restrict__ g,
    const float* __restrict__ b, float* __restrict__ scale,
    float* __restrict__ bias, float invN)
{
    const int c = threadIdx.x;
    const float mu = sums[c] * invN;
    const float var = sums[128 + c] * invN - mu * mu;
    const float rs = rsqrtf(var + 1e-5f);
    const float sc = g[c] * rs;
    scale[c] = sc;
    bias[c] = b[c] - mu * sc;
}

// =====================================================================
// CSR build v3 (bucket-binned, block-privatized reservations)
// =====================================================================
__global__ __launch_bounds__(256) void bucket_count_kernel(
    const int* __restrict__ edges, int* __restrict__ bcnt)
{
    const int r = blockIdx.y;
    __shared__ int sh[NBUCK];
    for (int i = threadIdx.x; i < NBUCK; i += 256) sh[i] = 0;
    __syncthreads();
    const int* trg = edges + (size_t)r * 2 * E_EDGES + E_EDGES;
    for (int i = blockIdx.x * 256 + threadIdx.x; i < E_EDGES; i += gridDim.x * 256)
        atomicAdd(&sh[trg[i] >> 7], 1);
    __syncthreads();
    for (int i = threadIdx.x; i < NBUCK; i += 256)
        if (sh[i]) atomicAdd(&bcnt[r * NBUCK + i], sh[i]);
}

__global__ __launch_bounds__(512) void bucket_scan_kernel(
    const int* __restrict__ bcnt, int* __restrict__ bscan,
    int* __restrict__ gbcur, int* __restrict__ rowptr)
{
    const int r = blockIdx.x;
    const int t = threadIdx.x;
    __shared__ int sh[512];
    const int v = (t < NBUCK) ? bcnt[r * NBUCK + t] : 0;
    sh[t] = v;
    __syncthreads();
    for (int off = 1; off < 512; off <<= 1) {
        const int u = (t >= off) ? sh[t - off] : 0;
        __syncthreads();
        sh[t] += u;
        __syncthreads();
    }
    if (t < NBUCK) {
        const int excl = sh[t] - v;
        bscan[r * NBUCK + t] = excl;
        gbcur[(r * NBUCK + t) * 16] = excl;
    }
    if (t == 0) rowptr[(size_t)r * (N_NODES + 1) + N_NODES] = E_EDGES;
}

__global__ __launch_bounds__(256) void bucket_bin_kernel(
    const int* __restrict__ edges, int* __restrict__ gbcur, int2* __restrict__ tmp)
{
    const int r = blockIdx.y;
    const int t = threadIdx.x;
    __shared__ int hist[NBUCK];
    __shared__ int basebuf[NBUCK];
    for (int b = t; b < NBUCK; b += 256) hist[b] = 0;
    __syncthreads();
    const int i0 = blockIdx.x * BIN_CHUNK;
    const int i1 = min(i0 + BIN_CHUNK, E_EDGES);
    const int* srcp = edges + (size_t)r * 2 * E_EDGES;
    const int* trgp = srcp + E_EDGES;
    for (int i = i0 + t; i < i1; i += 256)
        atomicAdd(&hist[trgp[i] >> 7], 1);
    __syncthreads();
    for (int b = t; b < NBUCK; b += 256) {
        const int c = hist[b];
        basebuf[b] = c ? atomicAdd(&gbcur[(r * NBUCK + b) * 16], c) : 0;
        hist[b] = 0;
    }
    __syncthreads();
    for (int i = i0 + t; i < i1; i += 256) {
        const int s = srcp[i], tg = trgp[i];
        const int b = tg >> 7;
        const int pos = basebuf[b] + atomicAdd(&hist[b], 1);
        tmp[(size_t)r * E_EDGES + pos] = make_int2(s, tg);
    }
}

__global__ __launch_bounds__(256) void bucket_finalize_kernel(
    const int2* __restrict__ tmp, const int* __restrict__ bscan,
    int* __restrict__ rowptr, int* __restrict__ srcs)
{
    const int r = blockIdx.y;
    const int b = blockIdx.x;
    const int n0 = b * 128;
    const int nn = min(128, N_NODES - n0);
    const int t = threadIdx.x;
    __shared__ int cnt[128];
    __shared__ int pos128[128];
    if (t < 128) cnt[t] = 0;
    __syncthreads();
    const int e0 = bscan[r * NBUCK + b];
    const int e1 = (b + 1 < NBUCK) ? bscan[r * NBUCK + b + 1] : E_EDGES;
    for (int i = e0 + t; i < e1; i += 256) {
        const int2 p = tmp[(size_t)r * E_EDGES + i];
        atomicAdd(&cnt[p.y - n0], 1);
    }
    __syncthreads();
    if (t < 128) pos128[t] = cnt[t];
    __syncthreads();
    for (int off = 1; off < 128; off <<= 1) {
        int u = 0;
        if (t < 128 && t >= off) u = pos128[t - off];
        __syncthreads();
        if (t < 128) pos128[t] += u;
        __syncthreads();
    }
    if (t < 128) {
        const int excl = pos128[t] - cnt[t];
        if (t < nn) rowptr[(size_t)r * (N_NODES + 1) + n0 + t] = e0 + excl;
        cnt[t] = e0 + excl;
    }
    __syncthreads();
    for (int i = e0 + t; i < e1; i += 256) {
        const int2 p = tmp[(size_t)r * E_EDGES + i];
        const int pos = atomicAdd(&cnt[p.y - n0], 1);
        srcs[(size_t)r * E_EDGES + pos] = p.x;
    }
}

// =====================================================================
// Aggregation (all 3 relations, grid.y = r): one wave per target node;
// 8-edge steps with fdot2 accumulate; residual from bf16 x.
// Epilogue: residual + leaky, write bf16 h.
// =====================================================================
__global__ __launch_bounds__(256) void agg_kernel(
    const int* __restrict__ rowptr_all, const int* __restrict__ srcs_all,
    const f16* __restrict__ gh, const float* __restrict__ el_all,
    const float* __restrict__ er_all, const unsigned* __restrict__ menc,
    const unsigned short* __restrict__ xbf, unsigned short* __restrict__ hbf)
{
    const int r = blockIdx.y;
    const int wid = (blockIdx.x * 256 + threadIdx.x) >> 6;
    const int lane = threadIdx.x & 63;
    if (wid >= N_NODES) return;
    const int* rowptr = rowptr_all + (size_t)r * (N_NODES + 1);
    const int* srcs = srcs_all + (size_t)r * E_EDGES;
    const float* el = el_all + (size_t)r * N_NODES * 8;
    const float* er = er_all + (size_t)r * N_NODES * 8;
    const int rbase = r * 128;
    float Ms = decf(menc[r * 2]) + decf(menc[r * 2 + 1]);
    const float M = Ms > 0.f ? Ms : 0.2f * Ms;
    const int l15 = lane & 15;
    const int sub = lane >> 4;
    const int hd = l15 >> 1;
    const float erv = er[(size_t)wid * 8 + hd];
    const int p0 = rowptr[wid], p1 = rowptr[wid + 1];
    float a[8] = {};
    float den = 0.f;
    for (int base = p0; base < p1; base += 64) {
        int sv = 0;
        if (base + lane < p1) sv = srcs[base + lane];
        const int nn = min(64, p1 - base);
        int j = 0;
        // main: 8 edges per step, 2 gathers in flight, fdot2 accumulate
        for (; j + 8 <= nn; j += 8) {
            const int s0 = __shfl(sv, j + sub, 64);
            const int s1 = __shfl(sv, j + 4 + sub, 64);
            const h8 g0 = *(const h8*)(gh + (size_t)s0 * 384 + rbase + l15 * 8);
            const h8 g1 = *(const h8*)(gh + (size_t)s1 * 384 + rbase + l15 * 8);
            float sc0 = el[(size_t)s0 * 8 + hd] + erv;
            float sc1 = el[(size_t)s1 * 8 + hd] + erv;
            sc0 = sc0 > 0.f ? sc0 : 0.2f * sc0;
            sc1 = sc1 > 0.f ? sc1 : 0.2f * sc1;
            const float e0 = __expf(sc0 - M);
            const float e1 = __expf(sc1 - M);
#if __has_builtin(__builtin_amdgcn_fdot2)
            h2v epk;
            epk[0] = (f16)e0; epk[1] = (f16)e1;
            #pragma unroll
            for (int c = 0; c < 8; ++c) {
                h2v gp;
                gp[0] = g0[c]; gp[1] = g1[c];
                a[c] = __builtin_amdgcn_fdot2(gp, epk, a[c], false);
            }
#else
            #pragma unroll
            for (int c = 0; c < 8; ++c) {
                a[c] = fmaf((float)g0[c], e0, a[c]);
                a[c] = fmaf((float)g1[c], e1, a[c]);
            }
#endif
            den += e0 + e1;
        }
        // tail: predicated 4-edge steps
        for (; j < nn; j += 4) {
            const int jj = j + sub;
            const int s = __shfl(sv, jj, 64);
            float ex = 0.f;
            if (jj < nn) {
                float sc = el[(size_t)s * 8 + hd] + erv;
                sc = sc > 0.f ? sc : 0.2f * sc;
                ex = __expf(sc - M);
            }
            const h8 gv = *(const h8*)(gh + (size_t)s * 384 + rbase + l15 * 8);
            #pragma unroll
            for (int c = 0; c < 8; ++c)
                a[c] = fmaf((float)gv[c], ex, a[c]);
            den += ex;
        }
    }
    #pragma unroll
    for (int c = 0; c < 8; ++c) {
        a[c] += __shfl_xor(a[c], 16, 64);
        a[c] += __shfl_xor(a[c], 32, 64);
    }
    den += __shfl_xor(den, 16, 64);
    den += __shfl_xor(den, 32, 64);
    if (lane < 16) {
        const float inv = 1.f / (den + 1e-16f);
        const size_t o = (size_t)wid * 384 + rbase + l15 * 8;
        const ushort8 xv = *(const ushort8*)(xbf + o);
        ushort8 vh;
        #pragma unroll
        for (int c = 0; c < 8; ++c) {
            float v = a[c] * inv;
            v = (v > 0.f ? v : 0.01f * v) + bf16f(xv[c]);
            vh[c] = bf16hi(v);
        }
        *(ushort8*)(hbf + o) = vh;
    }
}

// =====================================================================
extern "C" void kernel_launch(void* const* d_in, const int* in_sizes, int n_in,
                              void* d_out, int out_size, void* d_ws, size_t ws_size,
                              hipStream_t stream) {
    const float* inputs = (const float*)d_in[0];
    const int*   edges  = (const int*)d_in[1];
    const float* W_emb1 = (const float*)d_in[2];
    const float* W_emb2 = (const float*)d_in[3];
    const float* g_emb  = (const float*)d_in[4];
    const float* b_emb  = (const float*)d_in[5];
    const float* Wg     = (const float*)d_in[6];
    const float* al     = (const float*)d_in[7];
    const float* ar     = (const float*)d_in[8];
    const float* W_d1   = (const float*)d_in[9];
    const float* W_d2   = (const float*)d_in[10];
    const float* g_d    = (const float*)d_in[11];
    const float* b_d    = (const float*)d_in[12];
    float* out = (float*)d_out;

    char* base = (char*)d_ws;
    size_t off = 0;
    auto carve = [&](size_t bytes) {
        void* p = base + off;
        off = (off + bytes + 255) & ~(size_t)255;
        return p;
    };
    unsigned short* xbf = (unsigned short*)carve((size_t)N_NODES * D_F * 2); // 38.4 MB
    unsigned short* hbf = (unsigned short*)carve((size_t)N_NODES * D_F * 2); // 38.4
    f16*   tch = (f16*)carve((size_t)N_NODES * D_F * 2);                     // 38.4
    float* t1  = (float*)carve((size_t)N_NODES * HID_F * 4);                 // 25.6
    int2*  tmp = (int2*)tch;        // ALIAS (CSR build only, before tch written)
    float* el  = (float*)carve((size_t)R_REL * N_NODES * H_HEADS * 4);
    float* er  = (float*)carve((size_t)R_REL * N_NODES * H_HEADS * 4);
    unsigned short* wg_hi  = (unsigned short*)carve((size_t)L_LAYERS * NC_EXT * 384 * 2);
    unsigned short* we1_hi = (unsigned short*)carve((size_t)128 * 128 * 2);
    unsigned short* we2_hi = (unsigned short*)carve((size_t)128 * 384 * 2);
    unsigned short* wd1_hi = (unsigned short*)carve((size_t)384 * 128 * 2);
    float* sums  = (float*)carve(256 * 4);
    float* scale = (float*)carve(128 * 4);
    float* bias  = (float*)carve(128 * 4);
    unsigned* Menc = (unsigned*)carve((size_t)L_LAYERS * 8 * 4);
    int* rowptr = (int*)carve((size_t)R_REL * (N_NODES + 1) * 4);
    int* srcs   = (int*)carve((size_t)R_REL * E_EDGES * 4);
    int* bcnt   = (int*)carve((size_t)R_REL * NBUCK * 4);
    int* bscan  = (int*)carve((size_t)R_REL * NBUCK * 4);
    int* gbcur  = (int*)carve((size_t)R_REL * NBUCK * 16 * 4);

    // ---- weight preps (bf16 hi only) ----
    {
        int tot = L_LAYERS * 384 * 384;
        wg_split_kernel<<<(tot + 255) / 256, 256, 0, stream>>>(Wg, wg_hi);
        tot = L_LAYERS * 128 * 384;
        welr_build_kernel<<<(tot + 255) / 256, 256, 0, stream>>>(Wg, al, ar, wg_hi);
        tot = 128 * 128;
        wsplit_kernel<<<(tot + 255) / 256, 256, 0, stream>>>(W_emb1, we1_hi, 128, 128, tot);
        tot = 128 * 384;
        wsplit_kernel<<<(tot + 255) / 256, 256, 0, stream>>>(W_emb2, we2_hi, 128, 384, tot);
        tot = 384 * 128;
        wsplit_kernel<<<(tot + 255) / 256, 256, 0, stream>>>(W_d1, wd1_hi, 384, 128, tot);
    }

    // ---- CSR build + Menc reset ----
    hipMemsetAsync(bcnt, 0, (size_t)R_REL * NBUCK * 4, stream);
    hipMemsetAsync(Menc, 0, (size_t)L_LAYERS * 8 * 4, stream);
    {
        dim3 gc(256, R_REL);
        dim3 gbin((E_EDGES + BIN_CHUNK - 1) / BIN_CHUNK, R_REL);
        dim3 gb(NBUCK, R_REL);
        bucket_count_kernel<<<gc, 256, 0, stream>>>(edges, bcnt);
        bucket_scan_kernel<<<R_REL, 512, 0, stream>>>(bcnt, bscan, gbcur, rowptr);
        bucket_bin_kernel<<<gbin, 256, 0, stream>>>(edges, gbcur, tmp);
        bucket_finalize_kernel<<<gb, 256, 0, stream>>>(tmp, bscan, rowptr, srcs);
    }

    const int nrt8 = (NRT + 7) / 8;   // 49

    // ---- Embedding MLP: xbf = bf16( relu(BN(inputs@W_emb1)) @ W_emb2 ) ----
    {
        mfma_gemm<0, false, false><<<8 * 1 * nrt8, 256, 0, stream>>>(
            inputs, nullptr, we1_hi, t1, nullptr, nullptr,
            N_NODES, IN_F, HID_F, 1, nullptr, nullptr, nullptr, nullptr, nullptr);
        hipMemsetAsync(sums, 0, 256 * 4, stream);
        bn_stats_kernel<<<(N_NODES + 127) / 128, 256, 0, stream>>>(t1, sums, N_NODES);
        bn_final_kernel<<<1, 128, 0, stream>>>(sums, g_emb, b_emb, scale, bias, 1.0f / N_NODES);
        mfma_gemm<1, true, false><<<8 * 3 * nrt8, 256, 0, stream>>>(
            t1, nullptr, we2_hi, nullptr, xbf, nullptr,
            N_NODES, HID_F, D_F, 3, scale, bias, nullptr, nullptr, nullptr);
    }

    // ---- GAT layers (all PRESPLIT: layer 0 reads xbf, later layers hbf) ----
    for (int l = 0; l < L_LAYERS; ++l) {
        const unsigned short* hsrc = (l == 0) ? xbf : hbf;
        mfma_gemm<3, false, true><<<8 * 4 * nrt8, 256, 0, stream>>>(
            nullptr, hsrc, wg_hi + (size_t)l * NC_EXT * 384,
            nullptr, nullptr, tch, N_NODES, D_F, 384, 4, nullptr, nullptr,
            el, er, Menc + l * 8);
        dim3 ga((N_NODES * 64 + 255) / 256, R_REL);
        agg_kernel<<<ga, 256, 0, stream>>>(rowptr, srcs, tch, el, er,
                                           Menc + l * 8, xbf, hbf);
    }

    // ---- Decoder MLP: out = relu(BN(h@W_d1)) @ W_d2 ----
    {
        mfma_gemm<0, false, true><<<8 * 1 * nrt8, 256, 0, stream>>>(
            nullptr, hbf, wd1_hi, t1, nullptr, nullptr,
            N_NODES, D_F, HID_F, 1, nullptr, nullptr, nullptr, nullptr, nullptr);
        hipMemsetAsync(sums, 0, 256 * 4, stream);
        bn_stats_kernel<<<(N_NODES + 127) / 128, 256, 0, stream>>>(t1, sums, N_NODES);
        bn_final_kernel<<<1, 128, 0, stream>>>(sums, g_d, b_d, scale, bias, 1.0f / N_NODES);
        dim3 grid((N_NODES + 127) / 128, OUT_F / 64);
        gemm_kernel<true><<<grid, 256, 0, stream>>>(t1, W_d2, out, N_NODES, OUT_F, HID_F, scale, bias);
    }
}